// Round 11
// baseline (2222.631 us; speedup 1.0000x reference)
//
#include <hip/hip_runtime.h>

#define NB 64
#define NS 256
#define NH 1024
#define NE 512
#define NV 10000
#define NT 64
#define ND 512
#define NEH 1536
#define HST (65 * NH)   // element stride between batches in Hbuf[b][t][:]

typedef __attribute__((ext_vector_type(8))) short bf16x8;
typedef __attribute__((ext_vector_type(4))) float f32x4;

__device__ __forceinline__ short F2B(float f) {
  unsigned u = __float_as_uint(f);
  return (short)((u + 0x7fffu + ((u >> 16) & 1u)) >> 16);
}
__device__ __forceinline__ float B2F(short s) {
  return __uint_as_float(((unsigned)(unsigned short)s) << 16);
}
__device__ __forceinline__ float ftanh(float x) {
  float e = __expf(2.f * x);                 // inf for big x -> rcp -> 0 -> 1
  return 1.f - 2.f * __builtin_amdgcn_rcpf(e + 1.f);
}

#define GLD16(src, dst)                                                        \
  __builtin_amdgcn_global_load_lds(                                            \
      (const __attribute__((address_space(1))) void*)(src),                    \
      (__attribute__((address_space(3))) void*)(dst), 16, 0, 0)

// ---------------------------------------------------------------------------
// Fallback 64x64 tile (fp32 A staging) — used only for Uk when enc_h absent.
// ---------------------------------------------------------------------------
__device__ __forceinline__ void mm64_f32a(
    const float* __restrict__ Af, int lda, const short* __restrict__ Wg,
    int ldw, int K, short* Ch, size_t ldc, char* smem)
{
  const int tid = threadIdx.x;
  const int lane = tid & 63, w = tid >> 6;
  const int qm = (w >> 1) << 5, qn = (w & 1) << 5;
  const int kg = lane >> 4, rl = lane & 15;
  f32x4 acc[2][2] = {};
  const int nIt = K >> 6;

  auto stage = [&](int k0, int buf) {
    char* As = smem + (buf << 14);
    char* Bs = As + 8192;
#pragma unroll
    for (int p = 0; p < 2; ++p) {
      int j = tid + (p << 8);
      int row = j >> 3;
      int c = (j & 7) ^ (row & 7);
      const float* src = Af + (size_t)row * lda + k0 + (c << 3);
      float4 v0 = ((const float4*)src)[0];
      float4 v1 = ((const float4*)src)[1];
      bf16x8 pk;
      pk[0] = F2B(v0.x); pk[1] = F2B(v0.y); pk[2] = F2B(v0.z); pk[3] = F2B(v0.w);
      pk[4] = F2B(v1.x); pk[5] = F2B(v1.y); pk[6] = F2B(v1.z); pk[7] = F2B(v1.w);
      *((bf16x8*)As + j) = pk;
    }
#pragma unroll
    for (int p = 0; p < 2; ++p) {
      int j = (w << 7) + (p << 6) + lane;
      int row = j >> 3;
      int c = (j & 7) ^ (row & 7);
      GLD16(Wg + (size_t)row * ldw + k0 + (c << 3), Bs + (w << 11) + (p << 10));
    }
  };

  stage(0, 0);
  for (int it = 0; it < nIt; ++it) {
    __syncthreads();
    if (it + 1 < nIt) stage((it + 1) << 6, (it + 1) & 1);
    const short* As = (const short*)(smem + ((it & 1) << 14));
    const short* Bs = As + 4096;
#pragma unroll
    for (int kk = 0; kk < 2; ++kk) {
      bf16x8 af[2], bfr[2];
#pragma unroll
      for (int mt = 0; mt < 2; ++mt) {
        int r2 = qm + (mt << 4) + rl;
        int c = (kk << 2) + kg;
        af[mt] = *((const bf16x8*)As + ((r2 << 3) | (c ^ (r2 & 7))));
      }
#pragma unroll
      for (int nt = 0; nt < 2; ++nt) {
        int r2 = qn + (nt << 4) + rl;
        int c = (kk << 2) + kg;
        bfr[nt] = *((const bf16x8*)Bs + ((r2 << 3) | (c ^ (r2 & 7))));
      }
#pragma unroll
      for (int mt = 0; mt < 2; ++mt)
#pragma unroll
        for (int nt = 0; nt < 2; ++nt)
          acc[mt][nt] = __builtin_amdgcn_mfma_f32_16x16x32_bf16(
              af[mt], bfr[nt], acc[mt][nt], 0, 0, 0);
    }
  }
#pragma unroll
  for (int mt = 0; mt < 2; ++mt)
#pragma unroll
    for (int nt = 0; nt < 2; ++nt) {
      int cn = qn + (nt << 4) + rl;
#pragma unroll
      for (int r = 0; r < 4; ++r) {
        int rowm = qm + (mt << 4) + (kg << 2) + r;
        Ch[(size_t)rowm * ldc + cn] = F2B(acc[mt][nt][r]);
      }
    }
}

__global__ __launch_bounds__(256) void uk_mm_f32(const float* __restrict__ enc,
                                                 const short* __restrict__ Ua_h,
                                                 short* __restrict__ Uk_h) {
  __shared__ char smem[32768];
  mm64_f32a(enc + (size_t)blockIdx.y * 64 * NH, NH,
            Ua_h + (size_t)blockIdx.x * 64 * NH, NH, NH,
            Uk_h + (size_t)blockIdx.y * 64 * NH + blockIdx.x * 64, NH, smem);
}

// ---------------------------------------------------------------------------
// 128x128 bf16 tile GEMM, 2-deep pipelined LDS. Grid: x = m-tile, y = n-tile
// (consecutive blocks share the B n-panel for L2 reuse).
// MODE 0 = logits: A rows from Hbuf[b][t] via arow(m)=(m>>6)*65+(m&63)+1,
//          contiguous [B][T][V] fp32 store + bias.
// MODE 1 = Uk (plain A rows, bf16 store).
// ---------------------------------------------------------------------------
template <int MODE>
__global__ __launch_bounds__(256) void mm128p(
    const short* __restrict__ A, const short* __restrict__ Bw, int nvmax,
    const float* __restrict__ bias, float* __restrict__ Cf,
    short* __restrict__ Ch)
{
  __shared__ char smem[65536];
  const int tid = threadIdx.x, lane = tid & 63, w = tid >> 6;
  const int m0 = blockIdx.x << 7;
  const int n0 = blockIdx.y << 7;
  const int qm = (w >> 1) << 6, qn = (w & 1) << 6;
  const int kg = lane >> 4, rl = lane & 15;
  f32x4 acc[4][4] = {};

  auto stage = [&](int it, int buf) {
    char* dst = smem + (buf << 15);
    const int k0 = it << 6;
#pragma unroll
    for (int p = 0; p < 4; ++p) {
      int j = (((w << 2) + p) << 6) + lane;
      int row = j >> 3;
      int c = (j & 7) ^ (row & 7);
      int m = m0 + row;
      size_t arow = (MODE == 0) ? ((size_t)(m >> 6) * 65 + (m & 63) + 1)
                                : (size_t)m;
      GLD16(A + arow * NH + k0 + (c << 3), dst + (((w << 2) + p) << 10));
      int vr = n0 + row; if (vr > nvmax - 1) vr = nvmax - 1;
      GLD16(Bw + (size_t)vr * NH + k0 + (c << 3),
            dst + 16384 + (((w << 2) + p) << 10));
    }
  };

  stage(0, 0); stage(1, 1);
  for (int it = 0; it < 16; ++it) {
    if (it < 15) asm volatile("s_waitcnt vmcnt(8)" ::: "memory");
    else         asm volatile("s_waitcnt vmcnt(0)" ::: "memory");
    __builtin_amdgcn_s_barrier();
    __builtin_amdgcn_sched_barrier(0);
    const short* As = (const short*)(smem + ((it & 1) << 15));
    const short* Bs = As + 8192;
#pragma unroll
    for (int kk = 0; kk < 2; ++kk) {
      bf16x8 af[4], bfr[4];
#pragma unroll
      for (int mt = 0; mt < 4; ++mt) {
        int r2 = qm + (mt << 4) + rl;
        int c = (kk << 2) + kg;
        af[mt] = *((const bf16x8*)As + ((r2 << 3) | (c ^ (r2 & 7))));
      }
#pragma unroll
      for (int nt = 0; nt < 4; ++nt) {
        int r2 = qn + (nt << 4) + rl;
        int c = (kk << 2) + kg;
        bfr[nt] = *((const bf16x8*)Bs + ((r2 << 3) | (c ^ (r2 & 7))));
      }
#pragma unroll
      for (int mt = 0; mt < 4; ++mt)
#pragma unroll
        for (int nt = 0; nt < 4; ++nt)
          acc[mt][nt] = __builtin_amdgcn_mfma_f32_16x16x32_bf16(
              af[mt], bfr[nt], acc[mt][nt], 0, 0, 0);
    }
    __builtin_amdgcn_sched_barrier(0);
    __builtin_amdgcn_s_barrier();
    if (it + 2 < 16) stage(it + 2, it & 1);
  }
#pragma unroll
  for (int nt = 0; nt < 4; ++nt) {
    int colv = n0 + qn + (nt << 4) + rl;
    if (colv < nvmax) {
#pragma unroll
      for (int mt = 0; mt < 4; ++mt)
#pragma unroll
        for (int r = 0; r < 4; ++r) {
          int m = m0 + qm + (mt << 4) + (kg << 2) + r;
          if (MODE == 0) {
            Cf[(size_t)m * NV + colv] = acc[mt][nt][r] + bias[colv];
          } else {
            Ch[(size_t)m * NH + colv] = F2B(acc[mt][nt][r]);
          }
        }
    }
  }
}

// ---------------------------------------------------------------------------
// Fused attention: scores (no-max exp) + cross-block exchange via agent-scope
// atomics + softmax + ctx. Grid 256 = (b, part), 512 threads.
// part = s-slice [part*64, +64) in phase 1, h-quarter in phase 2.
// All 256 blocks are co-resident (18 KB LDS, 8 waves) -> spin is safe.
// ---------------------------------------------------------------------------
__global__ __launch_bounds__(512) void attn_one(
    const float* __restrict__ q, const short* __restrict__ Uk,
    const float* __restrict__ Va, const unsigned char* __restrict__ mask,
    const short* __restrict__ enc_h, const float* __restrict__ enc_f,
    int use_h, short* __restrict__ Xt, float* __restrict__ attn_out,
    unsigned* __restrict__ ebuf, unsigned* __restrict__ cnt, int t)
{
  __shared__ float qs[NH];
  __shared__ float vas[NH];
  __shared__ float eall[NS];
  __shared__ float wsm[NS];
  __shared__ float4 red4[512];
  __shared__ float redsum;
  const int tid = threadIdx.x;
  const int b = blockIdx.x >> 2, part = blockIdx.x & 3;
  const int lane = tid & 63, w = tid >> 6;

  {
    int i2 = tid << 1;
    *(float2*)(qs + i2) = *(const float2*)(q + (size_t)b * NH + i2);
    *(float2*)(vas + i2) = *(const float2*)(Va + i2);
  }
  __syncthreads();

  // ---- phase 1: 8 scores per wave, e = exp(score) (no max subtraction) ----
#pragma unroll 1
  for (int i = 0; i < 8; ++i) {
    const int s = (part << 6) + (w << 3) + i;
    const short* up = Uk + ((size_t)b * NS + s) * NH + (lane << 4);
    bf16x8 u0 = ((const bf16x8*)up)[0];
    bf16x8 u1 = ((const bf16x8*)up)[1];
    const float* qp = qs + (lane << 4);
    const float* vp = vas + (lane << 4);
    float a = 0.f;
#pragma unroll
    for (int j = 0; j < 8; ++j) a += vp[j] * ftanh(qp[j] + B2F(u0[j]));
#pragma unroll
    for (int j = 0; j < 8; ++j) a += vp[8 + j] * ftanh(qp[8 + j] + B2F(u1[j]));
#pragma unroll
    for (int o = 32; o; o >>= 1) a += __shfl_down(a, o);
    if (lane == 0) {
      float e = mask[b * NS + s] ? 0.f : __expf(a);
      __hip_atomic_store(&ebuf[b * NS + s], __float_as_uint(e),
                         __ATOMIC_RELAXED, __HIP_MEMORY_SCOPE_AGENT);
    }
  }
  // drain stores to the coherence point, then post + spin
  asm volatile("s_waitcnt vmcnt(0)" ::: "memory");
  __syncthreads();
  if (tid == 0) {
    __hip_atomic_fetch_add(&cnt[b << 4], 1u, __ATOMIC_RELAXED,
                           __HIP_MEMORY_SCOPE_AGENT);
    const unsigned tgt = 4u * (unsigned)(t + 1);
    while (__hip_atomic_load(&cnt[b << 4], __ATOMIC_RELAXED,
                             __HIP_MEMORY_SCOPE_AGENT) < tgt)
      __builtin_amdgcn_s_sleep(8);
  }
  __syncthreads();
  if (tid < NS)
    eall[tid] = __uint_as_float(__hip_atomic_load(
        &ebuf[b * NS + tid], __ATOMIC_RELAXED, __HIP_MEMORY_SCOPE_AGENT));
  __syncthreads();
  if (w == 0) {
    float su = eall[lane] + eall[lane + 64] + eall[lane + 128] +
               eall[lane + 192];
#pragma unroll
    for (int o = 32; o; o >>= 1) su += __shfl_down(su, o);
    if (lane == 0) redsum = su;
  }
  __syncthreads();
  {
    float inv = 1.f / redsum;
    if (tid < NS) {
      float ww = eall[tid] * inv;
      wsm[tid] = ww;
      if (part == 0) attn_out[((size_t)b * NT + t) * NS + tid] = ww;
    }
  }
  __syncthreads();

  // ---- phase 2: ctx for h-quarter `part` ----
  const int w8 = tid >> 6, l = tid & 63;
  const int h = (part << 8) + (l << 2);
  const int s0 = w8 << 5;
  float4 a4 = make_float4(0.f, 0.f, 0.f, 0.f);
  if (use_h) {
    const short* ep = enc_h + ((size_t)b * NS + s0) * NH + h;
#pragma unroll 8
    for (int s = 0; s < 32; ++s) {
      short4 vv = *(const short4*)(ep + (size_t)s * NH);
      float wv = wsm[s0 + s];
      a4.x += wv * B2F(vv.x); a4.y += wv * B2F(vv.y);
      a4.z += wv * B2F(vv.z); a4.w += wv * B2F(vv.w);
    }
  } else {
    const float* ep = enc_f + ((size_t)b * NS + s0) * NH + h;
#pragma unroll 8
    for (int s = 0; s < 32; ++s) {
      float4 vv = *(const float4*)(ep + (size_t)s * NH);
      float wv = wsm[s0 + s];
      a4.x += wv * vv.x; a4.y += wv * vv.y;
      a4.z += wv * vv.z; a4.w += wv * vv.w;
    }
  }
  red4[(w8 << 6) + l] = a4;
  __syncthreads();
  if (tid < 64) {
    float sx = 0.f, sy = 0.f, sz = 0.f, sw = 0.f;
#pragma unroll
    for (int k = 0; k < 8; ++k) {
      float4 r = red4[(k << 6) + tid];
      sx += r.x; sy += r.y; sz += r.z; sw += r.w;
    }
    short4 o;
    o.x = F2B(sx); o.y = F2B(sy); o.z = F2B(sz); o.w = F2B(sw);
    *(short4*)(Xt + (size_t)b * NEH + NE + (part << 8) + (tid << 2)) = o;
  }
}

// ---------------------------------------------------------------------------
// Pipelined skinny GEMM + fused LSTM cell. Grid 256 = dir(2) x gi(128).
// h rows read/written at HST stride (Hbuf[b][t] layout).
// ---------------------------------------------------------------------------
__global__ __launch_bounds__(256) void gates_v2(
    const short* __restrict__ Xt, const short* __restrict__ hcur,
    const short* __restrict__ Wcomb, const float* __restrict__ bperm,
    const float* __restrict__ cq_old, float* __restrict__ hq_f,
    float* __restrict__ cq_new, short* __restrict__ hnext)
{
  __shared__ char smem[61440];
  const int tid = threadIdx.x, lane = tid & 63, w = tid >> 6;
  const int kg = lane >> 4, rl = lane & 15;
  const int dir = blockIdx.x >> 7, gi = blockIdx.x & 127;
  const int hoff = dir << 9;
  const short* Wbase = Wcomb + (((size_t)(dir << 11) + (gi << 4)) << 11);

  auto stage = [&](int it, int buf) {
    char* dst = smem + buf * 20480;
#pragma unroll
    for (int g = 0; g < 4; ++g) {
      int row = (g << 4) + (w << 2) + kg;
      int c = rl ^ (row & 15);
      int k = (it << 7) + (c << 3);
      const short* src = (k < NEH)
          ? (Xt + (size_t)row * NEH + k)
          : (hcur + (size_t)row * HST + hoff + (k - NEH));
      GLD16(src, dst + (g << 12) + (w << 10));
    }
    {
      int rowB = (w << 2) + kg;
      int cB = rl ^ rowB;
      int kB = (it << 7) + (cB << 3);
      GLD16(Wbase + (size_t)rowB * 2048 + kB, dst + 16384 + (w << 10));
    }
  };

  stage(0, 0); stage(1, 1); stage(2, 2);
  f32x4 acc = {};
  int buf = 0;
  for (int it = 0; it < 16; ++it) {
    if (it < 14)      asm volatile("s_waitcnt vmcnt(10)" ::: "memory");
    else if (it == 14) asm volatile("s_waitcnt vmcnt(5)" ::: "memory");
    else               asm volatile("s_waitcnt vmcnt(0)" ::: "memory");
    __builtin_amdgcn_s_barrier();
    __builtin_amdgcn_sched_barrier(0);
    const short* As = (const short*)(smem + buf * 20480);
    const short* Bs = (const short*)(smem + buf * 20480 + 16384);
    const int rowA = (w << 4) + rl;
#pragma unroll
    for (int kk = 0; kk < 4; ++kk) {
      int chunk = (kk << 2) | kg;
      bf16x8 af = *((const bf16x8*)As + ((rowA << 4) | (chunk ^ (rowA & 15))));
      bf16x8 bf = *((const bf16x8*)Bs + ((rl << 4) | (chunk ^ rl)));
      acc = __builtin_amdgcn_mfma_f32_16x16x32_bf16(af, bf, acc, 0, 0, 0);
    }
    __builtin_amdgcn_sched_barrier(0);
    __builtin_amdgcn_s_barrier();
    if (it + 3 < 16) stage(it + 3, buf);
    buf = (buf == 2) ? 0 : buf + 1;
  }
  float* gacc = (float*)smem;                    // [64][17], overlays buf0
#pragma unroll
  for (int r = 0; r < 4; ++r)
    gacc[((w << 4) + (kg << 2) + r) * 17 + rl] = acc[r];
  __syncthreads();
  {
    const int b = tid >> 2, j2 = tid & 3;
    const float* bp = bperm + (dir << 11) + (gi << 4) + (j2 << 2);
    const float* gr = gacc + b * 17 + (j2 << 2);
    float gi_ = gr[0] + bp[0];
    float gf_ = gr[1] + bp[1];
    float gg_ = gr[2] + bp[2];
    float go_ = gr[3] + bp[3];
    const int d = ((gi >> 2) << 4) + (((gi << 2) + j2) & 15);
    const int idx = (b << 10) + hoff + d;
    float c0v = cq_old[idx];
    float si = 1.f / (1.f + __expf(-gi_));
    float sf = 1.f / (1.f + __expf(-gf_));
    float so = 1.f / (1.f + __expf(-go_));
    float tg = ftanh(gg_);
    float c2 = sf * c0v + si * tg;
    float h2 = so * ftanh(c2);
    hq_f[idx] = h2;
    cq_new[idx] = c2;
    hnext[(size_t)b * HST + hoff + d] = F2B(h2);
  }
}

// ---------------------------------------------------------------------------
// Pipelined q GEMM: grid 64 blocks, M=64, N=16, K=1024, BK=128, 3-deep.
// h rows read at HST stride.
// ---------------------------------------------------------------------------
__global__ __launch_bounds__(256) void q_mm2(const short* __restrict__ hcur,
                                             const short* __restrict__ Wa_h,
                                             float* __restrict__ q)
{
  __shared__ char smem[61440];
  const int tid = threadIdx.x, lane = tid & 63, w = tid >> 6;
  const int kg = lane >> 4, rl = lane & 15;
  const int n0 = blockIdx.x << 4;
  const short* Wbase = Wa_h + (size_t)n0 * NH;

  auto stage = [&](int it, int buf) {
    char* dst = smem + buf * 20480;
#pragma unroll
    for (int g = 0; g < 4; ++g) {
      int row = (g << 4) + (w << 2) + kg;
      int c = rl ^ (row & 15);
      int k = (it << 7) + (c << 3);
      GLD16(hcur + (size_t)row * HST + k, dst + (g << 12) + (w << 10));
    }
    {
      int rowB = (w << 2) + kg;
      int cB = rl ^ rowB;
      int kB = (it << 7) + (cB << 3);
      GLD16(Wbase + (size_t)rowB * NH + kB, dst + 16384 + (w << 10));
    }
  };

  stage(0, 0); stage(1, 1); stage(2, 2);
  f32x4 acc = {};
  int buf = 0;
  for (int it = 0; it < 8; ++it) {
    if (it < 6)       asm volatile("s_waitcnt vmcnt(10)" ::: "memory");
    else if (it == 6) asm volatile("s_waitcnt vmcnt(5)" ::: "memory");
    else              asm volatile("s_waitcnt vmcnt(0)" ::: "memory");
    __builtin_amdgcn_s_barrier();
    __builtin_amdgcn_sched_barrier(0);
    const short* As = (const short*)(smem + buf * 20480);
    const short* Bs = (const short*)(smem + buf * 20480 + 16384);
    const int rowA = (w << 4) + rl;
#pragma unroll
    for (int kk = 0; kk < 4; ++kk) {
      int chunk = (kk << 2) | kg;
      bf16x8 af = *((const bf16x8*)As + ((rowA << 4) | (chunk ^ (rowA & 15))));
      bf16x8 bf = *((const bf16x8*)Bs + ((rl << 4) | (chunk ^ rl)));
      acc = __builtin_amdgcn_mfma_f32_16x16x32_bf16(af, bf, acc, 0, 0, 0);
    }
    __builtin_amdgcn_sched_barrier(0);
    __builtin_amdgcn_s_barrier();
    if (it + 3 < 8) stage(it + 3, buf);
    buf = (buf == 2) ? 0 : buf + 1;
  }
#pragma unroll
  for (int r = 0; r < 4; ++r)
    q[(size_t)((w << 4) + (kg << 2) + r) * NH + n0 + rl] = acc[r];
}

// --- small kernels ----------------------------------------------------------
__global__ __launch_bounds__(256) void f2b_k(const float* __restrict__ in,
                                             short* __restrict__ out, int n4) {
  int i = blockIdx.x * 256 + threadIdx.x;
  const int stride = gridDim.x * 256;
  for (; i < n4; i += stride) {
    float4 v = ((const float4*)in)[i];
    short4 o;
    o.x = F2B(v.x); o.y = F2B(v.y); o.z = F2B(v.z); o.w = F2B(v.w);
    ((short4*)out)[i] = o;
  }
}

__global__ __launch_bounds__(256) void f2b2_k(
    const float* __restrict__ in0, short* __restrict__ out0,
    const float* __restrict__ in1, short* __restrict__ out1, int n4each) {
  int i = blockIdx.x * 256 + threadIdx.x;
  const int stride = gridDim.x * 256;
  for (; i < 2 * n4each; i += stride) {
    const float* in = (i < n4each) ? in0 : in1;
    short* out = (i < n4each) ? out0 : out1;
    int j = (i < n4each) ? i : i - n4each;
    float4 v = ((const float4*)in)[j];
    short4 o;
    o.x = F2B(v.x); o.y = F2B(v.y); o.z = F2B(v.z); o.w = F2B(v.w);
    ((short4*)out)[j] = o;
  }
}

__global__ __launch_bounds__(256) void perm_w(
    const float* __restrict__ Wih_f, const float* __restrict__ Whh_f,
    const float* __restrict__ Wih_b, const float* __restrict__ Whh_b,
    const float* __restrict__ bih_f, const float* __restrict__ bhh_f,
    const float* __restrict__ bih_b, const float* __restrict__ bhh_b,
    short* __restrict__ Wcomb, float* __restrict__ bias_perm)
{
  int i = blockIdx.x * 256 + threadIdx.x;        // [0, 2*2048*512)
  int k4 = i & 511;
  int np = (i >> 9) & 2047;
  int dir = i >> 20;
  int gate = np & 3, dlo = (np >> 2) & 15, dblk = np >> 6;
  int d = (dblk << 4) + dlo;
  int r = (gate << 9) + d;
  int k = k4 << 2;
  const float* Wih = dir ? Wih_b : Wih_f;
  const float* Whh = dir ? Whh_b : Whh_f;
  float4 v = (k < NEH) ? *(const float4*)(Wih + (size_t)r * NEH + k)
                       : *(const float4*)(Whh + (size_t)r * ND + (k - NEH));
  short4 o;
  o.x = F2B(v.x); o.y = F2B(v.y); o.z = F2B(v.z); o.w = F2B(v.w);
  *(short4*)(Wcomb + ((size_t)((dir << 11) + np) << 11) + k) = o;
  if (k4 == 0) {
    const float* bi = dir ? bih_b : bih_f;
    const float* bh = dir ? bhh_b : bhh_f;
    bias_perm[(dir << 11) + np] = bi[r] + bh[r];
  }
}

__global__ __launch_bounds__(256) void emb_fill(
    const float* __restrict__ emb, const int* __restrict__ target,
    const int* __restrict__ sos, short* __restrict__ Xbuf)
{
  int idx = blockIdx.x * 256 + threadIdx.x;      // [0, 64*64*128)
  int t = idx >> 13;
  int r = idx & 8191;
  int b = r >> 7, e4 = r & 127;
  int tok = (t == 0) ? sos[0] : target[b * NT + t - 1];
  float4 v = *(const float4*)(emb + (size_t)tok * NE + (e4 << 2));
  short4 o;
  o.x = F2B(v.x); o.y = F2B(v.y); o.z = F2B(v.z); o.w = F2B(v.w);
  *(short4*)(Xbuf + (size_t)(t * NB + b) * NEH + (e4 << 2)) = o;
}

__global__ __launch_bounds__(256) void init_state(
    const float* __restrict__ h0, const float* __restrict__ c0,
    float* __restrict__ hq, float* __restrict__ cq, short* __restrict__ H0) {
  int idx = blockIdx.x * 256 + threadIdx.x;
  int b = idx >> 10, dir = (idx >> 9) & 1, d = idx & 511;
  int src = dir * NB * ND + (b << 9) + d;
  float h = h0[src];
  hq[idx] = h;
  cq[idx] = c0[src];
  H0[(size_t)b * HST + (dir << 9) + d] = F2B(h);   // Hbuf[b][0][:]
}

__global__ __launch_bounds__(256) void final_state(
    const float* __restrict__ hq, const float* __restrict__ cq,
    float* __restrict__ out_h, float* __restrict__ out_c) {
  int idx = blockIdx.x * 256 + threadIdx.x;
  int dir = idx >> 15, r = idx & 32767, b = r >> 9, d = r & 511;
  int src = b * NH + dir * ND + d;
  out_h[idx] = hq[src];
  out_c[idx] = cq[src];
}

// ---------------------------------------------------------------------------
extern "C" void kernel_launch(void* const* d_in, const int* in_sizes, int n_in,
                              void* d_out, int out_size, void* d_ws, size_t ws_size,
                              hipStream_t stream)
{
  const float* enc    = (const float*)d_in[0];
  const float* h0     = (const float*)d_in[1];
  const float* c0     = (const float*)d_in[2];
  const int*   target = (const int*)d_in[3];
  const unsigned char* mask = (const unsigned char*)d_in[4];
  const int*   sos    = (const int*)d_in[5];
  const float* emb    = (const float*)d_in[6];
  const float* Wa     = (const float*)d_in[7];
  const float* Ua     = (const float*)d_in[8];
  const float* Va     = (const float*)d_in[9];
  const float* out_W  = (const float*)d_in[10];
  const float* out_b  = (const float*)d_in[11];
  const float* Wih_f  = (const float*)d_in[12];
  const float* Whh_f  = (const float*)d_in[13];
  const float* bih_f  = (const float*)d_in[14];
  const float* bhh_f  = (const float*)d_in[15];
  const float* Wih_b  = (const float*)d_in[16];
  const float* Whh_b  = (const float*)d_in[17];
  const float* bih_b  = (const float*)d_in[18];
  const float* bhh_b  = (const float*)d_in[19];

  float* out_dec  = (float*)d_out;                       // [B][T][V]
  float* out_h    = out_dec + (size_t)NB * NT * NV;      // [2][B][D]
  float* out_c    = out_h + 2 * NB * ND;                 // [2][B][D]
  float* out_attn = out_c + 2 * NB * ND;                 // [B][T][S]

  char* base = (char*)d_ws;
  size_t off = 0;
  auto alloc = [&](size_t bytes) -> char* {
    char* p = base + off;
    off += (bytes + 255) & ~(size_t)255;
    return p;
  };
  short* Uk_h  = (short*)alloc((size_t)NB * NS * NH * 2);     // 33.5 MB
  short* ow_h  = (short*)alloc((size_t)NV * NH * 2);          // 20.5 MB
  short* Ua_h  = (short*)alloc((size_t)NH * NH * 2);
  short* Wa_h  = (short*)alloc((size_t)NH * NH * 2);
  short* Wcomb = (short*)alloc((size_t)2 * 2048 * 2048 * 2);  // 16.8 MB
  float* bperm = (float*)alloc((size_t)2 * 2048 * 4);
  float* q     = (float*)alloc((size_t)NB * NH * 4);
  unsigned* ebuf = (unsigned*)alloc((size_t)NB * NS * 4);     // e values
  unsigned* cnt  = (unsigned*)alloc((size_t)NB * 16 * 4);     // per-b counters
  short* Xbuf  = (short*)alloc((size_t)NT * NB * NEH * 2);    // 12.6 MB
  float* hq    = (float*)alloc((size_t)NB * NH * 4);
  float* cq    = (float*)alloc((size_t)2 * NB * NH * 4);
  short* Hbuf  = (short*)alloc((size_t)NB * HST * 2);         // 8.5 MB [b][65][NH]
  short* enc_h = nullptr;
  int use_h = 0;
  if (off + (size_t)NB * NS * NH * 2 <= ws_size) {
    enc_h = (short*)alloc((size_t)NB * NS * NH * 2);          // 33.5 MB
    use_h = 1;
  }
  if (off > ws_size) return;  // insufficient scratch

  // ---- setup ----
  hipMemsetAsync(cnt, 0, (size_t)NB * 16 * 4, stream);
  f2b_k<<<dim3(2048), dim3(256), 0, stream>>>(out_W, ow_h, NV * NH / 4);
  f2b2_k<<<dim3(2048), dim3(256), 0, stream>>>(Ua, Ua_h, Wa, Wa_h, NH * NH / 4);
  perm_w<<<dim3(8192), dim3(256), 0, stream>>>(Wih_f, Whh_f, Wih_b, Whh_b,
                                               bih_f, bhh_f, bih_b, bhh_b,
                                               Wcomb, bperm);
  emb_fill<<<dim3(2048), dim3(256), 0, stream>>>(emb, target, sos, Xbuf);
  init_state<<<dim3(256), dim3(256), 0, stream>>>(h0, c0, hq, cq, Hbuf);
  if (use_h) {
    f2b_k<<<dim3(2048), dim3(256), 0, stream>>>(enc, enc_h, NB * NS * NH / 4);
    mm128p<1><<<dim3(128, 8), dim3(256), 0, stream>>>(enc_h, Ua_h, NH, nullptr,
                                                      nullptr, Uk_h);
  } else {
    uk_mm_f32<<<dim3(16, 256), dim3(256), 0, stream>>>(enc, Ua_h, Uk_h);
  }

  // ---- recurrent loop: 3 kernels per step ----
  for (int t = 0; t < NT; ++t) {
    const short* hcur = Hbuf + (size_t)t * NH;        // row b at + b*HST
    short* hnext = Hbuf + (size_t)(t + 1) * NH;
    float* cq_cur = cq + (t & 1) * (NB * NH);
    float* cq_nxt = cq + ((t & 1) ^ 1) * (NB * NH);
    short* Xt = Xbuf + (size_t)t * NB * NEH;

    q_mm2<<<dim3(64), dim3(256), 0, stream>>>(hcur, Wa_h, q);
    attn_one<<<dim3(256), dim3(512), 0, stream>>>(q, Uk_h, Va, mask,
                                                  enc_h, enc, use_h, Xt,
                                                  out_attn, ebuf, cnt, t);
    gates_v2<<<dim3(256), dim3(256), 0, stream>>>(Xt, hcur, Wcomb, bperm,
                                                  cq_cur, hq, cq_nxt, hnext);
  }

  // ---- batched vocab projection over all steps (A rows mapped from Hbuf) --
  mm128p<0><<<dim3(32, 79), dim3(256), 0, stream>>>(Hbuf, ow_h, NV,
                                                    out_b, out_dec, nullptr);
  final_state<<<dim3(256), dim3(256), 0, stream>>>(hq, cq, out_h, out_c);
}

// Round 12
// 2071.578 us; speedup vs baseline: 1.0729x; 1.0729x over previous
//
#include <hip/hip_runtime.h>

#define NB 64
#define NS 256
#define NH 1024
#define NE 512
#define NV 10000
#define NT 64
#define ND 512
#define NEH 1536
#define HST (65 * NH)   // element stride between batches in Hbuf[b][t][:]

typedef __attribute__((ext_vector_type(8))) short bf16x8;
typedef __attribute__((ext_vector_type(4))) float f32x4;

__device__ __forceinline__ short F2B(float f) {
  unsigned u = __float_as_uint(f);
  return (short)((u + 0x7fffu + ((u >> 16) & 1u)) >> 16);
}
__device__ __forceinline__ float B2F(short s) {
  return __uint_as_float(((unsigned)(unsigned short)s) << 16);
}
__device__ __forceinline__ float ftanh(float x) {
  float e = __expf(2.f * x);                 // inf for big x -> rcp -> 0 -> 1
  return 1.f - 2.f * __builtin_amdgcn_rcpf(e + 1.f);
}

#define GLD16(src, dst)                                                        \
  __builtin_amdgcn_global_load_lds(                                            \
      (const __attribute__((address_space(1))) void*)(src),                    \
      (__attribute__((address_space(3))) void*)(dst), 16, 0, 0)

// ---------------------------------------------------------------------------
// Fallback 64x64 tile (fp32 A staging) — used only for Uk when enc_h absent.
// ---------------------------------------------------------------------------
__device__ __forceinline__ void mm64_f32a(
    const float* __restrict__ Af, int lda, const short* __restrict__ Wg,
    int ldw, int K, short* Ch, size_t ldc, char* smem)
{
  const int tid = threadIdx.x;
  const int lane = tid & 63, w = tid >> 6;
  const int qm = (w >> 1) << 5, qn = (w & 1) << 5;
  const int kg = lane >> 4, rl = lane & 15;
  f32x4 acc[2][2] = {};
  const int nIt = K >> 6;

  auto stage = [&](int k0, int buf) {
    char* As = smem + (buf << 14);
    char* Bs = As + 8192;
#pragma unroll
    for (int p = 0; p < 2; ++p) {
      int j = tid + (p << 8);
      int row = j >> 3;
      int c = (j & 7) ^ (row & 7);
      const float* src = Af + (size_t)row * lda + k0 + (c << 3);
      float4 v0 = ((const float4*)src)[0];
      float4 v1 = ((const float4*)src)[1];
      bf16x8 pk;
      pk[0] = F2B(v0.x); pk[1] = F2B(v0.y); pk[2] = F2B(v0.z); pk[3] = F2B(v0.w);
      pk[4] = F2B(v1.x); pk[5] = F2B(v1.y); pk[6] = F2B(v1.z); pk[7] = F2B(v1.w);
      *((bf16x8*)As + j) = pk;
    }
#pragma unroll
    for (int p = 0; p < 2; ++p) {
      int j = (w << 7) + (p << 6) + lane;
      int row = j >> 3;
      int c = (j & 7) ^ (row & 7);
      GLD16(Wg + (size_t)row * ldw + k0 + (c << 3), Bs + (w << 11) + (p << 10));
    }
  };

  stage(0, 0);
  for (int it = 0; it < nIt; ++it) {
    __syncthreads();
    if (it + 1 < nIt) stage((it + 1) << 6, (it + 1) & 1);
    const short* As = (const short*)(smem + ((it & 1) << 14));
    const short* Bs = As + 4096;
#pragma unroll
    for (int kk = 0; kk < 2; ++kk) {
      bf16x8 af[2], bfr[2];
#pragma unroll
      for (int mt = 0; mt < 2; ++mt) {
        int r2 = qm + (mt << 4) + rl;
        int c = (kk << 2) + kg;
        af[mt] = *((const bf16x8*)As + ((r2 << 3) | (c ^ (r2 & 7))));
      }
#pragma unroll
      for (int nt = 0; nt < 2; ++nt) {
        int r2 = qn + (nt << 4) + rl;
        int c = (kk << 2) + kg;
        bfr[nt] = *((const bf16x8*)Bs + ((r2 << 3) | (c ^ (r2 & 7))));
      }
#pragma unroll
      for (int mt = 0; mt < 2; ++mt)
#pragma unroll
        for (int nt = 0; nt < 2; ++nt)
          acc[mt][nt] = __builtin_amdgcn_mfma_f32_16x16x32_bf16(
              af[mt], bfr[nt], acc[mt][nt], 0, 0, 0);
    }
  }
#pragma unroll
  for (int mt = 0; mt < 2; ++mt)
#pragma unroll
    for (int nt = 0; nt < 2; ++nt) {
      int cn = qn + (nt << 4) + rl;
#pragma unroll
      for (int r = 0; r < 4; ++r) {
        int rowm = qm + (mt << 4) + (kg << 2) + r;
        Ch[(size_t)rowm * ldc + cn] = F2B(acc[mt][nt][r]);
      }
    }
}

__global__ __launch_bounds__(256) void uk_mm_f32(const float* __restrict__ enc,
                                                 const short* __restrict__ Ua_h,
                                                 short* __restrict__ Uk_h) {
  __shared__ char smem[32768];
  mm64_f32a(enc + (size_t)blockIdx.y * 64 * NH, NH,
            Ua_h + (size_t)blockIdx.x * 64 * NH, NH, NH,
            Uk_h + (size_t)blockIdx.y * 64 * NH + blockIdx.x * 64, NH, smem);
}

// ---------------------------------------------------------------------------
// 128x128 bf16 tile GEMM, 2-deep pipelined LDS. Grid: x = m-tile, y = n-tile
// (consecutive blocks share the B n-panel for L2 reuse).
// MODE 0 = logits: A rows from Hbuf[b][t] via arow(m)=(m>>6)*65+(m&63)+1,
//          contiguous [B][T][V] fp32 store + bias.
// MODE 1 = Uk (plain A rows, bf16 store).
// ---------------------------------------------------------------------------
template <int MODE>
__global__ __launch_bounds__(256) void mm128p(
    const short* __restrict__ A, const short* __restrict__ Bw, int nvmax,
    const float* __restrict__ bias, float* __restrict__ Cf,
    short* __restrict__ Ch)
{
  __shared__ char smem[65536];
  const int tid = threadIdx.x, lane = tid & 63, w = tid >> 6;
  const int m0 = blockIdx.x << 7;
  const int n0 = blockIdx.y << 7;
  const int qm = (w >> 1) << 6, qn = (w & 1) << 6;
  const int kg = lane >> 4, rl = lane & 15;
  f32x4 acc[4][4] = {};

  auto stage = [&](int it, int buf) {
    char* dst = smem + (buf << 15);
    const int k0 = it << 6;
#pragma unroll
    for (int p = 0; p < 4; ++p) {
      int j = (((w << 2) + p) << 6) + lane;
      int row = j >> 3;
      int c = (j & 7) ^ (row & 7);
      int m = m0 + row;
      size_t arow = (MODE == 0) ? ((size_t)(m >> 6) * 65 + (m & 63) + 1)
                                : (size_t)m;
      GLD16(A + arow * NH + k0 + (c << 3), dst + (((w << 2) + p) << 10));
      int vr = n0 + row; if (vr > nvmax - 1) vr = nvmax - 1;
      GLD16(Bw + (size_t)vr * NH + k0 + (c << 3),
            dst + 16384 + (((w << 2) + p) << 10));
    }
  };

  stage(0, 0); stage(1, 1);
  for (int it = 0; it < 16; ++it) {
    if (it < 15) asm volatile("s_waitcnt vmcnt(8)" ::: "memory");
    else         asm volatile("s_waitcnt vmcnt(0)" ::: "memory");
    __builtin_amdgcn_s_barrier();
    __builtin_amdgcn_sched_barrier(0);
    const short* As = (const short*)(smem + ((it & 1) << 15));
    const short* Bs = As + 8192;
#pragma unroll
    for (int kk = 0; kk < 2; ++kk) {
      bf16x8 af[4], bfr[4];
#pragma unroll
      for (int mt = 0; mt < 4; ++mt) {
        int r2 = qm + (mt << 4) + rl;
        int c = (kk << 2) + kg;
        af[mt] = *((const bf16x8*)As + ((r2 << 3) | (c ^ (r2 & 7))));
      }
#pragma unroll
      for (int nt = 0; nt < 4; ++nt) {
        int r2 = qn + (nt << 4) + rl;
        int c = (kk << 2) + kg;
        bfr[nt] = *((const bf16x8*)Bs + ((r2 << 3) | (c ^ (r2 & 7))));
      }
#pragma unroll
      for (int mt = 0; mt < 4; ++mt)
#pragma unroll
        for (int nt = 0; nt < 4; ++nt)
          acc[mt][nt] = __builtin_amdgcn_mfma_f32_16x16x32_bf16(
              af[mt], bfr[nt], acc[mt][nt], 0, 0, 0);
    }
    __builtin_amdgcn_sched_barrier(0);
    __builtin_amdgcn_s_barrier();
    if (it + 2 < 16) stage(it + 2, it & 1);
  }
#pragma unroll
  for (int nt = 0; nt < 4; ++nt) {
    int colv = n0 + qn + (nt << 4) + rl;
    if (colv < nvmax) {
#pragma unroll
      for (int mt = 0; mt < 4; ++mt)
#pragma unroll
        for (int r = 0; r < 4; ++r) {
          int m = m0 + qm + (mt << 4) + (kg << 2) + r;
          if (MODE == 0) {
            Cf[(size_t)m * NV + colv] = acc[mt][nt][r] + bias[colv];
          } else {
            Ch[(size_t)m * NH + colv] = F2B(acc[mt][nt][r]);
          }
        }
    }
  }
}

// ---------------------------------------------------------------------------
// Pipelined skinny GEMM + fused LSTM cell. Grid 256 = dir(2) x gi(128).
// h rows read/written at HST stride (Hbuf[b][t] layout).
// ---------------------------------------------------------------------------
__global__ __launch_bounds__(256) void gates_v2(
    const short* __restrict__ Xt, const short* __restrict__ hcur,
    const short* __restrict__ Wcomb, const float* __restrict__ bperm,
    const float* __restrict__ cq_old, float* __restrict__ hq_f,
    float* __restrict__ cq_new, short* __restrict__ hnext)
{
  __shared__ char smem[61440];
  const int tid = threadIdx.x, lane = tid & 63, w = tid >> 6;
  const int kg = lane >> 4, rl = lane & 15;
  const int dir = blockIdx.x >> 7, gi = blockIdx.x & 127;
  const int hoff = dir << 9;
  const short* Wbase = Wcomb + (((size_t)(dir << 11) + (gi << 4)) << 11);

  auto stage = [&](int it, int buf) {
    char* dst = smem + buf * 20480;
#pragma unroll
    for (int g = 0; g < 4; ++g) {
      int row = (g << 4) + (w << 2) + kg;
      int c = rl ^ (row & 15);
      int k = (it << 7) + (c << 3);
      const short* src = (k < NEH)
          ? (Xt + (size_t)row * NEH + k)
          : (hcur + (size_t)row * HST + hoff + (k - NEH));
      GLD16(src, dst + (g << 12) + (w << 10));
    }
    {
      int rowB = (w << 2) + kg;
      int cB = rl ^ rowB;
      int kB = (it << 7) + (cB << 3);
      GLD16(Wbase + (size_t)rowB * 2048 + kB, dst + 16384 + (w << 10));
    }
  };

  stage(0, 0); stage(1, 1); stage(2, 2);
  f32x4 acc = {};
  int buf = 0;
  for (int it = 0; it < 16; ++it) {
    if (it < 14)      asm volatile("s_waitcnt vmcnt(10)" ::: "memory");
    else if (it == 14) asm volatile("s_waitcnt vmcnt(5)" ::: "memory");
    else               asm volatile("s_waitcnt vmcnt(0)" ::: "memory");
    __builtin_amdgcn_s_barrier();
    __builtin_amdgcn_sched_barrier(0);
    const short* As = (const short*)(smem + buf * 20480);
    const short* Bs = (const short*)(smem + buf * 20480 + 16384);
    const int rowA = (w << 4) + rl;
#pragma unroll
    for (int kk = 0; kk < 4; ++kk) {
      int chunk = (kk << 2) | kg;
      bf16x8 af = *((const bf16x8*)As + ((rowA << 4) | (chunk ^ (rowA & 15))));
      bf16x8 bf = *((const bf16x8*)Bs + ((rl << 4) | (chunk ^ rl)));
      acc = __builtin_amdgcn_mfma_f32_16x16x32_bf16(af, bf, acc, 0, 0, 0);
    }
    __builtin_amdgcn_sched_barrier(0);
    __builtin_amdgcn_s_barrier();
    if (it + 3 < 16) stage(it + 3, buf);
    buf = (buf == 2) ? 0 : buf + 1;
  }
  float* gacc = (float*)smem;                    // [64][17], overlays buf0
#pragma unroll
  for (int r = 0; r < 4; ++r)
    gacc[((w << 4) + (kg << 2) + r) * 17 + rl] = acc[r];
  __syncthreads();
  {
    const int b = tid >> 2, j2 = tid & 3;
    const float* bp = bperm + (dir << 11) + (gi << 4) + (j2 << 2);
    const float* gr = gacc + b * 17 + (j2 << 2);
    float gi_ = gr[0] + bp[0];
    float gf_ = gr[1] + bp[1];
    float gg_ = gr[2] + bp[2];
    float go_ = gr[3] + bp[3];
    const int d = ((gi >> 2) << 4) + (((gi << 2) + j2) & 15);
    const int idx = (b << 10) + hoff + d;
    float c0v = cq_old[idx];
    float si = 1.f / (1.f + __expf(-gi_));
    float sf = 1.f / (1.f + __expf(-gf_));
    float so = 1.f / (1.f + __expf(-go_));
    float tg = ftanh(gg_);
    float c2 = sf * c0v + si * tg;
    float h2 = so * ftanh(c2);
    hq_f[idx] = h2;
    cq_new[idx] = c2;
    hnext[(size_t)b * HST + hoff + d] = F2B(h2);
  }
}

// ---------------------------------------------------------------------------
// Pipelined q GEMM: grid 64 blocks, M=64, N=16, K=1024, BK=128, 3-deep.
// h rows read at HST stride.
// ---------------------------------------------------------------------------
__global__ __launch_bounds__(256) void q_mm2(const short* __restrict__ hcur,
                                             const short* __restrict__ Wa_h,
                                             float* __restrict__ q)
{
  __shared__ char smem[61440];
  const int tid = threadIdx.x, lane = tid & 63, w = tid >> 6;
  const int kg = lane >> 4, rl = lane & 15;
  const int n0 = blockIdx.x << 4;
  const short* Wbase = Wa_h + (size_t)n0 * NH;

  auto stage = [&](int it, int buf) {
    char* dst = smem + buf * 20480;
#pragma unroll
    for (int g = 0; g < 4; ++g) {
      int row = (g << 4) + (w << 2) + kg;
      int c = rl ^ (row & 15);
      int k = (it << 7) + (c << 3);
      GLD16(hcur + (size_t)row * HST + k, dst + (g << 12) + (w << 10));
    }
    {
      int rowB = (w << 2) + kg;
      int cB = rl ^ rowB;
      int kB = (it << 7) + (cB << 3);
      GLD16(Wbase + (size_t)rowB * NH + kB, dst + 16384 + (w << 10));
    }
  };

  stage(0, 0); stage(1, 1); stage(2, 2);
  f32x4 acc = {};
  int buf = 0;
  for (int it = 0; it < 8; ++it) {
    if (it < 6)       asm volatile("s_waitcnt vmcnt(10)" ::: "memory");
    else if (it == 6) asm volatile("s_waitcnt vmcnt(5)" ::: "memory");
    else              asm volatile("s_waitcnt vmcnt(0)" ::: "memory");
    __builtin_amdgcn_s_barrier();
    __builtin_amdgcn_sched_barrier(0);
    const short* As = (const short*)(smem + buf * 20480);
    const short* Bs = (const short*)(smem + buf * 20480 + 16384);
    const int rowA = (w << 4) + rl;
#pragma unroll
    for (int kk = 0; kk < 4; ++kk) {
      int chunk = (kk << 2) | kg;
      bf16x8 af = *((const bf16x8*)As + ((rowA << 4) | (chunk ^ (rowA & 15))));
      bf16x8 bf = *((const bf16x8*)Bs + ((rl << 4) | (chunk ^ rl)));
      acc = __builtin_amdgcn_mfma_f32_16x16x32_bf16(af, bf, acc, 0, 0, 0);
    }
    __builtin_amdgcn_sched_barrier(0);
    __builtin_amdgcn_s_barrier();
    if (it + 3 < 8) stage(it + 3, buf);
    buf = (buf == 2) ? 0 : buf + 1;
  }
#pragma unroll
  for (int r = 0; r < 4; ++r)
    q[(size_t)((w << 4) + (kg << 2) + r) * NH + n0 + rl] = acc[r];
}

// --- small kernels ----------------------------------------------------------
__global__ __launch_bounds__(256) void f2b_k(const float* __restrict__ in,
                                             short* __restrict__ out, int n4) {
  int i = blockIdx.x * 256 + threadIdx.x;
  const int stride = gridDim.x * 256;
  for (; i < n4; i += stride) {
    float4 v = ((const float4*)in)[i];
    short4 o;
    o.x = F2B(v.x); o.y = F2B(v.y); o.z = F2B(v.z); o.w = F2B(v.w);
    ((short4*)out)[i] = o;
  }
}

__global__ __launch_bounds__(256) void f2b2_k(
    const float* __restrict__ in0, short* __restrict__ out0,
    const float* __restrict__ in1, short* __restrict__ out1, int n4each) {
  int i = blockIdx.x * 256 + threadIdx.x;
  const int stride = gridDim.x * 256;
  for (; i < 2 * n4each; i += stride) {
    const float* in = (i < n4each) ? in0 : in1;
    short* out = (i < n4each) ? out0 : out1;
    int j = (i < n4each) ? i : i - n4each;
    float4 v = ((const float4*)in)[j];
    short4 o;
    o.x = F2B(v.x); o.y = F2B(v.y); o.z = F2B(v.z); o.w = F2B(v.w);
    ((short4*)out)[j] = o;
  }
}

__global__ __launch_bounds__(256) void perm_w(
    const float* __restrict__ Wih_f, const float* __restrict__ Whh_f,
    const float* __restrict__ Wih_b, const float* __restrict__ Whh_b,
    const float* __restrict__ bih_f, const float* __restrict__ bhh_f,
    const float* __restrict__ bih_b, const float* __restrict__ bhh_b,
    short* __restrict__ Wcomb, float* __restrict__ bias_perm)
{
  int i = blockIdx.x * 256 + threadIdx.x;        // [0, 2*2048*512)
  int k4 = i & 511;
  int np = (i >> 9) & 2047;
  int dir = i >> 20;
  int gate = np & 3, dlo = (np >> 2) & 15, dblk = np >> 6;
  int d = (dblk << 4) + dlo;
  int r = (gate << 9) + d;
  int k = k4 << 2;
  const float* Wih = dir ? Wih_b : Wih_f;
  const float* Whh = dir ? Whh_b : Whh_f;
  float4 v = (k < NEH) ? *(const float4*)(Wih + (size_t)r * NEH + k)
                       : *(const float4*)(Whh + (size_t)r * ND + (k - NEH));
  short4 o;
  o.x = F2B(v.x); o.y = F2B(v.y); o.z = F2B(v.z); o.w = F2B(v.w);
  *(short4*)(Wcomb + ((size_t)((dir << 11) + np) << 11) + k) = o;
  if (k4 == 0) {
    const float* bi = dir ? bih_b : bih_f;
    const float* bh = dir ? bhh_b : bhh_f;
    bias_perm[(dir << 11) + np] = bi[r] + bh[r];
  }
}

__global__ __launch_bounds__(256) void emb_fill(
    const float* __restrict__ emb, const int* __restrict__ target,
    const int* __restrict__ sos, short* __restrict__ Xbuf)
{
  int idx = blockIdx.x * 256 + threadIdx.x;      // [0, 64*64*128)
  int t = idx >> 13;
  int r = idx & 8191;
  int b = r >> 7, e4 = r & 127;
  int tok = (t == 0) ? sos[0] : target[b * NT + t - 1];
  float4 v = *(const float4*)(emb + (size_t)tok * NE + (e4 << 2));
  short4 o;
  o.x = F2B(v.x); o.y = F2B(v.y); o.z = F2B(v.z); o.w = F2B(v.w);
  *(short4*)(Xbuf + (size_t)(t * NB + b) * NEH + (e4 << 2)) = o;
}

__global__ __launch_bounds__(256) void init_state(
    const float* __restrict__ h0, const float* __restrict__ c0,
    float* __restrict__ hq, float* __restrict__ cq, short* __restrict__ H0) {
  int idx = blockIdx.x * 256 + threadIdx.x;
  int b = idx >> 10, dir = (idx >> 9) & 1, d = idx & 511;
  int src = dir * NB * ND + (b << 9) + d;
  float h = h0[src];
  hq[idx] = h;
  cq[idx] = c0[src];
  H0[(size_t)b * HST + (dir << 9) + d] = F2B(h);   // Hbuf[b][0][:]
}

__global__ __launch_bounds__(256) void final_state(
    const float* __restrict__ hq, const float* __restrict__ cq,
    float* __restrict__ out_h, float* __restrict__ out_c) {
  int idx = blockIdx.x * 256 + threadIdx.x;
  int dir = idx >> 15, r = idx & 32767, b = r >> 9, d = r & 511;
  int src = b * NH + dir * ND + d;
  out_h[idx] = hq[src];
  out_c[idx] = cq[src];
}

// one wave per (b,s); q[b] staged in LDS once per block (4 s per block)
// grid MUST be NB*NS/4 = 4096 blocks (b = blockIdx.x>>6).
__global__ __launch_bounds__(256) void attn_score(
    const float* __restrict__ q, const short* __restrict__ Uk,
    const float* __restrict__ Va, const unsigned char* __restrict__ mask,
    float* __restrict__ sc) {
  __shared__ float qs[NH];
  const int b = blockIdx.x >> 6;
  {
    int t4 = threadIdx.x << 2;
    *(float4*)(qs + t4) = *(const float4*)(q + (size_t)b * NH + t4);
  }
  __syncthreads();
  const int lane = threadIdx.x & 63, wid = threadIdx.x >> 6;
  const int bs = (blockIdx.x << 2) + wid;
  const short* ukp = Uk + (size_t)bs * NH;
  float acc = 0.f;
#pragma unroll
  for (int i = 0; i < 2; ++i) {
    int h = (i << 9) + (lane << 3);
    bf16x8 uv = *(const bf16x8*)(ukp + h);
    float4 q0 = *(const float4*)(qs + h);
    float4 q1 = *(const float4*)(qs + h + 4);
    float4 v0 = *(const float4*)(Va + h);
    float4 v1 = *(const float4*)(Va + h + 4);
    acc += v0.x * ftanh(q0.x + B2F(uv[0]));
    acc += v0.y * ftanh(q0.y + B2F(uv[1]));
    acc += v0.z * ftanh(q0.z + B2F(uv[2]));
    acc += v0.w * ftanh(q0.w + B2F(uv[3]));
    acc += v1.x * ftanh(q1.x + B2F(uv[4]));
    acc += v1.y * ftanh(q1.y + B2F(uv[5]));
    acc += v1.z * ftanh(q1.z + B2F(uv[6]));
    acc += v1.w * ftanh(q1.w + B2F(uv[7]));
  }
#pragma unroll
  for (int o = 32; o; o >>= 1) acc += __shfl_down(acc, o);
  if (lane == 0) sc[bs] = mask[bs] ? -__builtin_inff() : acc;
}

// 256 blocks x 512 threads: (b, h-quarter) softmax + ctx -> Xt[:, E:E+H]
__global__ __launch_bounds__(512) void ctx_soft(
    const float* __restrict__ sc, const short* __restrict__ enc_h,
    const float* __restrict__ enc_f, int use_h,
    short* __restrict__ Xt, float* __restrict__ attn_out, int t) {
  const int tid = threadIdx.x;
  const int b = blockIdx.x >> 2, qh = blockIdx.x & 3;
  __shared__ float red[8];
  __shared__ float ws[NS];
  __shared__ float4 red4[512];
  const int s8 = tid & 255;
  float v = sc[b * NS + s8];
  float m = v;
#pragma unroll
  for (int o = 32; o; o >>= 1) m = fmaxf(m, __shfl_down(m, o));
  if ((tid & 63) == 0) red[tid >> 6] = m;
  __syncthreads();
  m = fmaxf(fmaxf(fmaxf(red[0], red[1]), fmaxf(red[2], red[3])),
            fmaxf(fmaxf(red[4], red[5]), fmaxf(red[6], red[7])));
  float e = __expf(v - m);
  float su = e;
#pragma unroll
  for (int o = 32; o; o >>= 1) su += __shfl_down(su, o);
  __syncthreads();
  if ((tid & 63) == 0) red[tid >> 6] = su;
  __syncthreads();
  su = red[0] + red[1] + red[2] + red[3];   // waves 0-3 cover all 256 s
  float wgt = e / su;
  ws[s8] = wgt;                       // duplicate identical writes are benign
  if (qh == 0 && tid < 256) attn_out[((size_t)b * NT + t) * NS + tid] = wgt;
  __syncthreads();
  const int w8 = tid >> 6, l = tid & 63;
  const int h = (qh << 8) + (l << 2);
  const int s0 = w8 << 5;
  float4 a = make_float4(0.f, 0.f, 0.f, 0.f);
  if (use_h) {
    const short* ep = enc_h + ((size_t)b * NS + s0) * NH + h;
    for (int s = 0; s < 32; ++s) {
      short4 vv = *(const short4*)(ep + (size_t)s * NH);
      float wv = ws[s0 + s];
      a.x += wv * B2F(vv.x); a.y += wv * B2F(vv.y);
      a.z += wv * B2F(vv.z); a.w += wv * B2F(vv.w);
    }
  } else {
    const float* ep = enc_f + ((size_t)b * NS + s0) * NH + h;
    for (int s = 0; s < 32; ++s) {
      float4 vv = *(const float4*)(ep + (size_t)s * NH);
      float wv = ws[s0 + s];
      a.x += wv * vv.x; a.y += wv * vv.y; a.z += wv * vv.z; a.w += wv * vv.w;
    }
  }
  red4[(w8 << 6) + l] = a;
  __syncthreads();
  if (tid < 64) {
    float sx = 0.f, sy = 0.f, sz = 0.f, sw = 0.f;
#pragma unroll
    for (int k = 0; k < 8; ++k) {
      float4 r = red4[(k << 6) + tid];
      sx += r.x; sy += r.y; sz += r.z; sw += r.w;
    }
    short4 o;
    o.x = F2B(sx); o.y = F2B(sy); o.z = F2B(sz); o.w = F2B(sw);
    *(short4*)(Xt + (size_t)b * NEH + NE + (qh << 8) + (tid << 2)) = o;
  }
}

// ---------------------------------------------------------------------------
extern "C" void kernel_launch(void* const* d_in, const int* in_sizes, int n_in,
                              void* d_out, int out_size, void* d_ws, size_t ws_size,
                              hipStream_t stream)
{
  const float* enc    = (const float*)d_in[0];
  const float* h0     = (const float*)d_in[1];
  const float* c0     = (const float*)d_in[2];
  const int*   target = (const int*)d_in[3];
  const unsigned char* mask = (const unsigned char*)d_in[4];
  const int*   sos    = (const int*)d_in[5];
  const float* emb    = (const float*)d_in[6];
  const float* Wa     = (const float*)d_in[7];
  const float* Ua     = (const float*)d_in[8];
  const float* Va     = (const float*)d_in[9];
  const float* out_W  = (const float*)d_in[10];
  const float* out_b  = (const float*)d_in[11];
  const float* Wih_f  = (const float*)d_in[12];
  const float* Whh_f  = (const float*)d_in[13];
  const float* bih_f  = (const float*)d_in[14];
  const float* bhh_f  = (const float*)d_in[15];
  const float* Wih_b  = (const float*)d_in[16];
  const float* Whh_b  = (const float*)d_in[17];
  const float* bih_b  = (const float*)d_in[18];
  const float* bhh_b  = (const float*)d_in[19];

  float* out_dec  = (float*)d_out;                       // [B][T][V]
  float* out_h    = out_dec + (size_t)NB * NT * NV;      // [2][B][D]
  float* out_c    = out_h + 2 * NB * ND;                 // [2][B][D]
  float* out_attn = out_c + 2 * NB * ND;                 // [B][T][S]

  char* base = (char*)d_ws;
  size_t off = 0;
  auto alloc = [&](size_t bytes) -> char* {
    char* p = base + off;
    off += (bytes + 255) & ~(size_t)255;
    return p;
  };
  short* Uk_h  = (short*)alloc((size_t)NB * NS * NH * 2);     // 33.5 MB
  short* ow_h  = (short*)alloc((size_t)NV * NH * 2);          // 20.5 MB
  short* Ua_h  = (short*)alloc((size_t)NH * NH * 2);
  short* Wa_h  = (short*)alloc((size_t)NH * NH * 2);
  short* Wcomb = (short*)alloc((size_t)2 * 2048 * 2048 * 2);  // 16.8 MB
  float* bperm = (float*)alloc((size_t)2 * 2048 * 4);
  float* q     = (float*)alloc((size_t)NB * NH * 4);
  float* sc    = (float*)alloc((size_t)NB * NS * 4);
  short* Xbuf  = (short*)alloc((size_t)NT * NB * NEH * 2);    // 12.6 MB
  float* hq    = (float*)alloc((size_t)NB * NH * 4);
  float* cq    = (float*)alloc((size_t)2 * NB * NH * 4);
  short* Hbuf  = (short*)alloc((size_t)NB * HST * 2);         // 8.5 MB [b][65][NH]
  short* enc_h = nullptr;
  int use_h = 0;
  if (off + (size_t)NB * NS * NH * 2 <= ws_size) {
    enc_h = (short*)alloc((size_t)NB * NS * NH * 2);          // 33.5 MB
    use_h = 1;
  }
  if (off > ws_size) return;  // insufficient scratch

  // ---- setup ----
  f2b_k<<<dim3(2048), dim3(256), 0, stream>>>(out_W, ow_h, NV * NH / 4);
  f2b2_k<<<dim3(2048), dim3(256), 0, stream>>>(Ua, Ua_h, Wa, Wa_h, NH * NH / 4);
  perm_w<<<dim3(8192), dim3(256), 0, stream>>>(Wih_f, Whh_f, Wih_b, Whh_b,
                                               bih_f, bhh_f, bih_b, bhh_b,
                                               Wcomb, bperm);
  emb_fill<<<dim3(2048), dim3(256), 0, stream>>>(emb, target, sos, Xbuf);
  init_state<<<dim3(256), dim3(256), 0, stream>>>(h0, c0, hq, cq, Hbuf);
  if (use_h) {
    f2b_k<<<dim3(2048), dim3(256), 0, stream>>>(enc, enc_h, NB * NS * NH / 4);
    mm128p<1><<<dim3(128, 8), dim3(256), 0, stream>>>(enc_h, Ua_h, NH, nullptr,
                                                      nullptr, Uk_h);
  } else {
    uk_mm_f32<<<dim3(16, 256), dim3(256), 0, stream>>>(enc, Ua_h, Uk_h);
  }

  // ---- recurrent loop: 4 kernels per step ----
  for (int t = 0; t < NT; ++t) {
    const short* hcur = Hbuf + (size_t)t * NH;        // row b at + b*HST
    short* hnext = Hbuf + (size_t)(t + 1) * NH;
    float* cq_cur = cq + (t & 1) * (NB * NH);
    float* cq_nxt = cq + ((t & 1) ^ 1) * (NB * NH);
    short* Xt = Xbuf + (size_t)t * NB * NEH;

    q_mm2<<<dim3(64), dim3(256), 0, stream>>>(hcur, Wa_h, q);
    attn_score<<<dim3(4096), dim3(256), 0, stream>>>(q, Uk_h, Va, mask, sc);
    ctx_soft<<<dim3(256), dim3(512), 0, stream>>>(sc, enc_h, enc, use_h,
                                                  Xt, out_attn, t);
    gates_v2<<<dim3(256), dim3(256), 0, stream>>>(Xt, hcur, Wcomb, bperm,
                                                  cq_cur, hq, cq_nxt, hnext);
  }

  // ---- batched vocab projection over all steps (A rows mapped from Hbuf) --
  mm128p<0><<<dim3(32, 79), dim3(256), 0, stream>>>(Hbuf, ow_h, NV,
                                                    out_b, out_dec, nullptr);
  final_state<<<dim3(256), dim3(256), 0, stream>>>(hq, cq, out_h, out_c);
}

// Round 13
// 1971.889 us; speedup vs baseline: 1.1272x; 1.0506x over previous
//
#include <hip/hip_runtime.h>

#define NB 64
#define NS 256
#define NH 1024
#define NE 512
#define NV 10000
#define NT 64
#define ND 512
#define NEH 1536
#define HST (65 * NH)   // element stride between batches in Hbuf[b][t][:]

typedef __attribute__((ext_vector_type(8))) short bf16x8;
typedef __attribute__((ext_vector_type(4))) float f32x4;

__device__ __forceinline__ short F2B(float f) {
  unsigned u = __float_as_uint(f);
  return (short)((u + 0x7fffu + ((u >> 16) & 1u)) >> 16);
}
__device__ __forceinline__ float B2F(short s) {
  return __uint_as_float(((unsigned)(unsigned short)s) << 16);
}
__device__ __forceinline__ float ftanh(float x) {
  float e = __expf(2.f * x);                 // inf for big x -> rcp -> 0 -> 1
  return 1.f - 2.f * __builtin_amdgcn_rcpf(e + 1.f);
}

#define GLD16(src, dst)                                                        \
  __builtin_amdgcn_global_load_lds(                                            \
      (const __attribute__((address_space(1))) void*)(src),                    \
      (__attribute__((address_space(3))) void*)(dst), 16, 0, 0)

// ---------------------------------------------------------------------------
// Fallback 64x64 tile (fp32 A staging) — used only for Uk when enc_h absent.
// ---------------------------------------------------------------------------
__device__ __forceinline__ void mm64_f32a(
    const float* __restrict__ Af, int lda, const short* __restrict__ Wg,
    int ldw, int K, short* Ch, size_t ldc, char* smem)
{
  const int tid = threadIdx.x;
  const int lane = tid & 63, w = tid >> 6;
  const int qm = (w >> 1) << 5, qn = (w & 1) << 5;
  const int kg = lane >> 4, rl = lane & 15;
  f32x4 acc[2][2] = {};
  const int nIt = K >> 6;

  auto stage = [&](int k0, int buf) {
    char* As = smem + (buf << 14);
    char* Bs = As + 8192;
#pragma unroll
    for (int p = 0; p < 2; ++p) {
      int j = tid + (p << 8);
      int row = j >> 3;
      int c = (j & 7) ^ (row & 7);
      const float* src = Af + (size_t)row * lda + k0 + (c << 3);
      float4 v0 = ((const float4*)src)[0];
      float4 v1 = ((const float4*)src)[1];
      bf16x8 pk;
      pk[0] = F2B(v0.x); pk[1] = F2B(v0.y); pk[2] = F2B(v0.z); pk[3] = F2B(v0.w);
      pk[4] = F2B(v1.x); pk[5] = F2B(v1.y); pk[6] = F2B(v1.z); pk[7] = F2B(v1.w);
      *((bf16x8*)As + j) = pk;
    }
#pragma unroll
    for (int p = 0; p < 2; ++p) {
      int j = (w << 7) + (p << 6) + lane;
      int row = j >> 3;
      int c = (j & 7) ^ (row & 7);
      GLD16(Wg + (size_t)row * ldw + k0 + (c << 3), Bs + (w << 11) + (p << 10));
    }
  };

  stage(0, 0);
  for (int it = 0; it < nIt; ++it) {
    __syncthreads();
    if (it + 1 < nIt) stage((it + 1) << 6, (it + 1) & 1);
    const short* As = (const short*)(smem + ((it & 1) << 14));
    const short* Bs = As + 4096;
#pragma unroll
    for (int kk = 0; kk < 2; ++kk) {
      bf16x8 af[2], bfr[2];
#pragma unroll
      for (int mt = 0; mt < 2; ++mt) {
        int r2 = qm + (mt << 4) + rl;
        int c = (kk << 2) + kg;
        af[mt] = *((const bf16x8*)As + ((r2 << 3) | (c ^ (r2 & 7))));
      }
#pragma unroll
      for (int nt = 0; nt < 2; ++nt) {
        int r2 = qn + (nt << 4) + rl;
        int c = (kk << 2) + kg;
        bfr[nt] = *((const bf16x8*)Bs + ((r2 << 3) | (c ^ (r2 & 7))));
      }
#pragma unroll
      for (int mt = 0; mt < 2; ++mt)
#pragma unroll
        for (int nt = 0; nt < 2; ++nt)
          acc[mt][nt] = __builtin_amdgcn_mfma_f32_16x16x32_bf16(
              af[mt], bfr[nt], acc[mt][nt], 0, 0, 0);
    }
  }
#pragma unroll
  for (int mt = 0; mt < 2; ++mt)
#pragma unroll
    for (int nt = 0; nt < 2; ++nt) {
      int cn = qn + (nt << 4) + rl;
#pragma unroll
      for (int r = 0; r < 4; ++r) {
        int rowm = qm + (mt << 4) + (kg << 2) + r;
        Ch[(size_t)rowm * ldc + cn] = F2B(acc[mt][nt][r]);
      }
    }
}

__global__ __launch_bounds__(256) void uk_mm_f32(const float* __restrict__ enc,
                                                 const short* __restrict__ Ua_h,
                                                 short* __restrict__ Uk_h) {
  __shared__ char smem[32768];
  mm64_f32a(enc + (size_t)blockIdx.y * 64 * NH, NH,
            Ua_h + (size_t)blockIdx.x * 64 * NH, NH, NH,
            Uk_h + (size_t)blockIdx.y * 64 * NH + blockIdx.x * 64, NH, smem);
}

// ---------------------------------------------------------------------------
// 128x128 bf16 tile GEMM, 2-deep pipelined LDS. Grid: x = m-tile, y = n-tile
// (consecutive blocks share the B n-panel for L2 reuse).
// MODE 0 = logits: A rows from Hbuf[b][t] via arow(m)=(m>>6)*65+(m&63)+1,
//          contiguous [B][T][V] fp32 store + bias.
// MODE 1 = Uk (plain A rows, bf16 store).
// ---------------------------------------------------------------------------
template <int MODE>
__global__ __launch_bounds__(256) void mm128p(
    const short* __restrict__ A, const short* __restrict__ Bw, int nvmax,
    const float* __restrict__ bias, float* __restrict__ Cf,
    short* __restrict__ Ch)
{
  __shared__ char smem[65536];
  const int tid = threadIdx.x, lane = tid & 63, w = tid >> 6;
  const int m0 = blockIdx.x << 7;
  const int n0 = blockIdx.y << 7;
  const int qm = (w >> 1) << 6, qn = (w & 1) << 6;
  const int kg = lane >> 4, rl = lane & 15;
  f32x4 acc[4][4] = {};

  auto stage = [&](int it, int buf) {
    char* dst = smem + (buf << 15);
    const int k0 = it << 6;
#pragma unroll
    for (int p = 0; p < 4; ++p) {
      int j = (((w << 2) + p) << 6) + lane;
      int row = j >> 3;
      int c = (j & 7) ^ (row & 7);
      int m = m0 + row;
      size_t arow = (MODE == 0) ? ((size_t)(m >> 6) * 65 + (m & 63) + 1)
                                : (size_t)m;
      GLD16(A + arow * NH + k0 + (c << 3), dst + (((w << 2) + p) << 10));
      int vr = n0 + row; if (vr > nvmax - 1) vr = nvmax - 1;
      GLD16(Bw + (size_t)vr * NH + k0 + (c << 3),
            dst + 16384 + (((w << 2) + p) << 10));
    }
  };

  stage(0, 0); stage(1, 1);
  for (int it = 0; it < 16; ++it) {
    if (it < 15) asm volatile("s_waitcnt vmcnt(8)" ::: "memory");
    else         asm volatile("s_waitcnt vmcnt(0)" ::: "memory");
    __builtin_amdgcn_s_barrier();
    __builtin_amdgcn_sched_barrier(0);
    const short* As = (const short*)(smem + ((it & 1) << 15));
    const short* Bs = As + 8192;
#pragma unroll
    for (int kk = 0; kk < 2; ++kk) {
      bf16x8 af[4], bfr[4];
#pragma unroll
      for (int mt = 0; mt < 4; ++mt) {
        int r2 = qm + (mt << 4) + rl;
        int c = (kk << 2) + kg;
        af[mt] = *((const bf16x8*)As + ((r2 << 3) | (c ^ (r2 & 7))));
      }
#pragma unroll
      for (int nt = 0; nt < 4; ++nt) {
        int r2 = qn + (nt << 4) + rl;
        int c = (kk << 2) + kg;
        bfr[nt] = *((const bf16x8*)Bs + ((r2 << 3) | (c ^ (r2 & 7))));
      }
#pragma unroll
      for (int mt = 0; mt < 4; ++mt)
#pragma unroll
        for (int nt = 0; nt < 4; ++nt)
          acc[mt][nt] = __builtin_amdgcn_mfma_f32_16x16x32_bf16(
              af[mt], bfr[nt], acc[mt][nt], 0, 0, 0);
    }
    __builtin_amdgcn_sched_barrier(0);
    __builtin_amdgcn_s_barrier();
    if (it + 2 < 16) stage(it + 2, it & 1);
  }
#pragma unroll
  for (int nt = 0; nt < 4; ++nt) {
    int colv = n0 + qn + (nt << 4) + rl;
    if (colv < nvmax) {
#pragma unroll
      for (int mt = 0; mt < 4; ++mt)
#pragma unroll
        for (int r = 0; r < 4; ++r) {
          int m = m0 + qm + (mt << 4) + (kg << 2) + r;
          if (MODE == 0) {
            Cf[(size_t)m * NV + colv] = acc[mt][nt][r] + bias[colv];
          } else {
            Ch[(size_t)m * NH + colv] = F2B(acc[mt][nt][r]);
          }
        }
    }
  }
}

// ---------------------------------------------------------------------------
// Pipelined skinny GEMM + fused LSTM cell. Grid 256 = dir(2) x gi(128).
// h rows read/written at HST stride (Hbuf[b][t] layout).
// ---------------------------------------------------------------------------
__global__ __launch_bounds__(256) void gates_v2(
    const short* __restrict__ Xt, const short* __restrict__ hcur,
    const short* __restrict__ Wcomb, const float* __restrict__ bperm,
    const float* __restrict__ cq_old, float* __restrict__ hq_f,
    float* __restrict__ cq_new, short* __restrict__ hnext)
{
  __shared__ char smem[61440];
  const int tid = threadIdx.x, lane = tid & 63, w = tid >> 6;
  const int kg = lane >> 4, rl = lane & 15;
  const int dir = blockIdx.x >> 7, gi = blockIdx.x & 127;
  const int hoff = dir << 9;
  const short* Wbase = Wcomb + (((size_t)(dir << 11) + (gi << 4)) << 11);

  auto stage = [&](int it, int buf) {
    char* dst = smem + buf * 20480;
#pragma unroll
    for (int g = 0; g < 4; ++g) {
      int row = (g << 4) + (w << 2) + kg;
      int c = rl ^ (row & 15);
      int k = (it << 7) + (c << 3);
      const short* src = (k < NEH)
          ? (Xt + (size_t)row * NEH + k)
          : (hcur + (size_t)row * HST + hoff + (k - NEH));
      GLD16(src, dst + (g << 12) + (w << 10));
    }
    {
      int rowB = (w << 2) + kg;
      int cB = rl ^ rowB;
      int kB = (it << 7) + (cB << 3);
      GLD16(Wbase + (size_t)rowB * 2048 + kB, dst + 16384 + (w << 10));
    }
  };

  stage(0, 0); stage(1, 1); stage(2, 2);
  f32x4 acc = {};
  int buf = 0;
  for (int it = 0; it < 16; ++it) {
    if (it < 14)      asm volatile("s_waitcnt vmcnt(10)" ::: "memory");
    else if (it == 14) asm volatile("s_waitcnt vmcnt(5)" ::: "memory");
    else               asm volatile("s_waitcnt vmcnt(0)" ::: "memory");
    __builtin_amdgcn_s_barrier();
    __builtin_amdgcn_sched_barrier(0);
    const short* As = (const short*)(smem + buf * 20480);
    const short* Bs = (const short*)(smem + buf * 20480 + 16384);
    const int rowA = (w << 4) + rl;
#pragma unroll
    for (int kk = 0; kk < 4; ++kk) {
      int chunk = (kk << 2) | kg;
      bf16x8 af = *((const bf16x8*)As + ((rowA << 4) | (chunk ^ (rowA & 15))));
      bf16x8 bf = *((const bf16x8*)Bs + ((rl << 4) | (chunk ^ rl)));
      acc = __builtin_amdgcn_mfma_f32_16x16x32_bf16(af, bf, acc, 0, 0, 0);
    }
    __builtin_amdgcn_sched_barrier(0);
    __builtin_amdgcn_s_barrier();
    if (it + 3 < 16) stage(it + 3, buf);
    buf = (buf == 2) ? 0 : buf + 1;
  }
  float* gacc = (float*)smem;                    // [64][17], overlays buf0
#pragma unroll
  for (int r = 0; r < 4; ++r)
    gacc[((w << 4) + (kg << 2) + r) * 17 + rl] = acc[r];
  __syncthreads();
  {
    const int b = tid >> 2, j2 = tid & 3;
    const float* bp = bperm + (dir << 11) + (gi << 4) + (j2 << 2);
    const float* gr = gacc + b * 17 + (j2 << 2);
    float gi_ = gr[0] + bp[0];
    float gf_ = gr[1] + bp[1];
    float gg_ = gr[2] + bp[2];
    float go_ = gr[3] + bp[3];
    const int d = ((gi >> 2) << 4) + (((gi << 2) + j2) & 15);
    const int idx = (b << 10) + hoff + d;
    float c0v = cq_old[idx];
    float si = 1.f / (1.f + __expf(-gi_));
    float sf = 1.f / (1.f + __expf(-gf_));
    float so = 1.f / (1.f + __expf(-go_));
    float tg = ftanh(gg_);
    float c2 = sf * c0v + si * tg;
    float h2 = so * ftanh(c2);
    hq_f[idx] = h2;
    cq_new[idx] = c2;
    hnext[(size_t)b * HST + hoff + d] = F2B(h2);
  }
}

// ---------------------------------------------------------------------------
// Pipelined q GEMM: grid 64 blocks, M=64, N=16, K=1024, BK=128, 3-deep.
// h rows read at HST stride.
// ---------------------------------------------------------------------------
__global__ __launch_bounds__(256) void q_mm2(const short* __restrict__ hcur,
                                             const short* __restrict__ Wa_h,
                                             float* __restrict__ q)
{
  __shared__ char smem[61440];
  const int tid = threadIdx.x, lane = tid & 63, w = tid >> 6;
  const int kg = lane >> 4, rl = lane & 15;
  const int n0 = blockIdx.x << 4;
  const short* Wbase = Wa_h + (size_t)n0 * NH;

  auto stage = [&](int it, int buf) {
    char* dst = smem + buf * 20480;
#pragma unroll
    for (int g = 0; g < 4; ++g) {
      int row = (g << 4) + (w << 2) + kg;
      int c = rl ^ (row & 15);
      int k = (it << 7) + (c << 3);
      GLD16(hcur + (size_t)row * HST + k, dst + (g << 12) + (w << 10));
    }
    {
      int rowB = (w << 2) + kg;
      int cB = rl ^ rowB;
      int kB = (it << 7) + (cB << 3);
      GLD16(Wbase + (size_t)rowB * NH + kB, dst + 16384 + (w << 10));
    }
  };

  stage(0, 0); stage(1, 1); stage(2, 2);
  f32x4 acc = {};
  int buf = 0;
  for (int it = 0; it < 8; ++it) {
    if (it < 6)       asm volatile("s_waitcnt vmcnt(10)" ::: "memory");
    else if (it == 6) asm volatile("s_waitcnt vmcnt(5)" ::: "memory");
    else              asm volatile("s_waitcnt vmcnt(0)" ::: "memory");
    __builtin_amdgcn_s_barrier();
    __builtin_amdgcn_sched_barrier(0);
    const short* As = (const short*)(smem + buf * 20480);
    const short* Bs = (const short*)(smem + buf * 20480 + 16384);
    const int rowA = (w << 4) + rl;
#pragma unroll
    for (int kk = 0; kk < 4; ++kk) {
      int chunk = (kk << 2) | kg;
      bf16x8 af = *((const bf16x8*)As + ((rowA << 4) | (chunk ^ (rowA & 15))));
      bf16x8 bf = *((const bf16x8*)Bs + ((rl << 4) | (chunk ^ rl)));
      acc = __builtin_amdgcn_mfma_f32_16x16x32_bf16(af, bf, acc, 0, 0, 0);
    }
    __builtin_amdgcn_sched_barrier(0);
    __builtin_amdgcn_s_barrier();
    if (it + 3 < 8) stage(it + 3, buf);
    buf = (buf == 2) ? 0 : buf + 1;
  }
#pragma unroll
  for (int r = 0; r < 4; ++r)
    q[(size_t)((w << 4) + (kg << 2) + r) * NH + n0 + rl] = acc[r];
}

// --- small kernels ----------------------------------------------------------
__global__ __launch_bounds__(256) void f2b_k(const float* __restrict__ in,
                                             short* __restrict__ out, int n4) {
  int i = blockIdx.x * 256 + threadIdx.x;
  const int stride = gridDim.x * 256;
  for (; i < n4; i += stride) {
    float4 v = ((const float4*)in)[i];
    short4 o;
    o.x = F2B(v.x); o.y = F2B(v.y); o.z = F2B(v.z); o.w = F2B(v.w);
    ((short4*)out)[i] = o;
  }
}

// fp32 -> bf16 AND fp8(e4m3) in one pass (for enc)
__global__ __launch_bounds__(256) void f2b8_k(const float* __restrict__ in,
                                              short* __restrict__ outb,
                                              unsigned* __restrict__ out8,
                                              int n4) {
  int i = blockIdx.x * 256 + threadIdx.x;
  const int stride = gridDim.x * 256;
  for (; i < n4; i += stride) {
    float4 v = ((const float4*)in)[i];
    short4 o;
    o.x = F2B(v.x); o.y = F2B(v.y); o.z = F2B(v.z); o.w = F2B(v.w);
    ((short4*)outb)[i] = o;
    if (out8) {
      int u = __builtin_amdgcn_cvt_pk_fp8_f32(v.x, v.y, 0, false);
      u = __builtin_amdgcn_cvt_pk_fp8_f32(v.z, v.w, u, true);
      out8[i] = (unsigned)u;
    }
  }
}

__global__ __launch_bounds__(256) void f2b2_k(
    const float* __restrict__ in0, short* __restrict__ out0,
    const float* __restrict__ in1, short* __restrict__ out1, int n4each) {
  int i = blockIdx.x * 256 + threadIdx.x;
  const int stride = gridDim.x * 256;
  for (; i < 2 * n4each; i += stride) {
    const float* in = (i < n4each) ? in0 : in1;
    short* out = (i < n4each) ? out0 : out1;
    int j = (i < n4each) ? i : i - n4each;
    float4 v = ((const float4*)in)[j];
    short4 o;
    o.x = F2B(v.x); o.y = F2B(v.y); o.z = F2B(v.z); o.w = F2B(v.w);
    ((short4*)out)[j] = o;
  }
}

__global__ __launch_bounds__(256) void perm_w(
    const float* __restrict__ Wih_f, const float* __restrict__ Whh_f,
    const float* __restrict__ Wih_b, const float* __restrict__ Whh_b,
    const float* __restrict__ bih_f, const float* __restrict__ bhh_f,
    const float* __restrict__ bih_b, const float* __restrict__ bhh_b,
    short* __restrict__ Wcomb, float* __restrict__ bias_perm)
{
  int i = blockIdx.x * 256 + threadIdx.x;        // [0, 2*2048*512)
  int k4 = i & 511;
  int np = (i >> 9) & 2047;
  int dir = i >> 20;
  int gate = np & 3, dlo = (np >> 2) & 15, dblk = np >> 6;
  int d = (dblk << 4) + dlo;
  int r = (gate << 9) + d;
  int k = k4 << 2;
  const float* Wih = dir ? Wih_b : Wih_f;
  const float* Whh = dir ? Whh_b : Whh_f;
  float4 v = (k < NEH) ? *(const float4*)(Wih + (size_t)r * NEH + k)
                       : *(const float4*)(Whh + (size_t)r * ND + (k - NEH));
  short4 o;
  o.x = F2B(v.x); o.y = F2B(v.y); o.z = F2B(v.z); o.w = F2B(v.w);
  *(short4*)(Wcomb + ((size_t)((dir << 11) + np) << 11) + k) = o;
  if (k4 == 0) {
    const float* bi = dir ? bih_b : bih_f;
    const float* bh = dir ? bhh_b : bhh_f;
    bias_perm[(dir << 11) + np] = bi[r] + bh[r];
  }
}

__global__ __launch_bounds__(256) void emb_fill(
    const float* __restrict__ emb, const int* __restrict__ target,
    const int* __restrict__ sos, short* __restrict__ Xbuf)
{
  int idx = blockIdx.x * 256 + threadIdx.x;      // [0, 64*64*128)
  int t = idx >> 13;
  int r = idx & 8191;
  int b = r >> 7, e4 = r & 127;
  int tok = (t == 0) ? sos[0] : target[b * NT + t - 1];
  float4 v = *(const float4*)(emb + (size_t)tok * NE + (e4 << 2));
  short4 o;
  o.x = F2B(v.x); o.y = F2B(v.y); o.z = F2B(v.z); o.w = F2B(v.w);
  *(short4*)(Xbuf + (size_t)(t * NB + b) * NEH + (e4 << 2)) = o;
}

__global__ __launch_bounds__(256) void init_state(
    const float* __restrict__ h0, const float* __restrict__ c0,
    float* __restrict__ hq, float* __restrict__ cq, short* __restrict__ H0) {
  int idx = blockIdx.x * 256 + threadIdx.x;
  int b = idx >> 10, dir = (idx >> 9) & 1, d = idx & 511;
  int src = dir * NB * ND + (b << 9) + d;
  float h = h0[src];
  hq[idx] = h;
  cq[idx] = c0[src];
  H0[(size_t)b * HST + (dir << 9) + d] = F2B(h);   // Hbuf[b][0][:]
}

__global__ __launch_bounds__(256) void final_state(
    const float* __restrict__ hq, const float* __restrict__ cq,
    float* __restrict__ out_h, float* __restrict__ out_c) {
  int idx = blockIdx.x * 256 + threadIdx.x;
  int dir = idx >> 15, r = idx & 32767, b = r >> 9, d = r & 511;
  int src = b * NH + dir * ND + d;
  out_h[idx] = hq[src];
  out_c[idx] = cq[src];
}

// one wave per (b,s); q[b] staged in LDS once per block (4 s per block)
// grid MUST be NB*NS/4 = 4096 blocks (b = blockIdx.x>>6).
__global__ __launch_bounds__(256) void attn_score(
    const float* __restrict__ q, const short* __restrict__ Uk,
    const float* __restrict__ Va, const unsigned char* __restrict__ mask,
    float* __restrict__ sc) {
  __shared__ float qs[NH];
  const int b = blockIdx.x >> 6;
  {
    int t4 = threadIdx.x << 2;
    *(float4*)(qs + t4) = *(const float4*)(q + (size_t)b * NH + t4);
  }
  __syncthreads();
  const int lane = threadIdx.x & 63, wid = threadIdx.x >> 6;
  const int bs = (blockIdx.x << 2) + wid;
  const short* ukp = Uk + (size_t)bs * NH;
  float acc = 0.f;
#pragma unroll
  for (int i = 0; i < 2; ++i) {
    int h = (i << 9) + (lane << 3);
    bf16x8 uv = *(const bf16x8*)(ukp + h);
    float4 q0 = *(const float4*)(qs + h);
    float4 q1 = *(const float4*)(qs + h + 4);
    float4 v0 = *(const float4*)(Va + h);
    float4 v1 = *(const float4*)(Va + h + 4);
    acc += v0.x * ftanh(q0.x + B2F(uv[0]));
    acc += v0.y * ftanh(q0.y + B2F(uv[1]));
    acc += v0.z * ftanh(q0.z + B2F(uv[2]));
    acc += v0.w * ftanh(q0.w + B2F(uv[3]));
    acc += v1.x * ftanh(q1.x + B2F(uv[4]));
    acc += v1.y * ftanh(q1.y + B2F(uv[5]));
    acc += v1.z * ftanh(q1.z + B2F(uv[6]));
    acc += v1.w * ftanh(q1.w + B2F(uv[7]));
  }
#pragma unroll
  for (int o = 32; o; o >>= 1) acc += __shfl_down(acc, o);
  if (lane == 0) sc[bs] = mask[bs] ? -__builtin_inff() : acc;
}

// 256 blocks x 512 threads: (b, h-quarter) softmax + ctx -> Xt[:, E:E+H]
// use_8: read fp8 e4m3 enc copy (half the stream) via HW cvt_f32_fp8.
__global__ __launch_bounds__(512) void ctx_soft(
    const float* __restrict__ sc, const unsigned char* __restrict__ enc8,
    const short* __restrict__ enc_h, const float* __restrict__ enc_f,
    int use_8, int use_h,
    short* __restrict__ Xt, float* __restrict__ attn_out, int t) {
  const int tid = threadIdx.x;
  const int b = blockIdx.x >> 2, qh = blockIdx.x & 3;
  __shared__ float red[8];
  __shared__ float ws[NS];
  __shared__ float4 red4[512];
  const int s8 = tid & 255;
  float v = sc[b * NS + s8];
  float m = v;
#pragma unroll
  for (int o = 32; o; o >>= 1) m = fmaxf(m, __shfl_down(m, o));
  if ((tid & 63) == 0) red[tid >> 6] = m;
  __syncthreads();
  m = fmaxf(fmaxf(fmaxf(red[0], red[1]), fmaxf(red[2], red[3])),
            fmaxf(fmaxf(red[4], red[5]), fmaxf(red[6], red[7])));
  float e = __expf(v - m);
  float su = e;
#pragma unroll
  for (int o = 32; o; o >>= 1) su += __shfl_down(su, o);
  __syncthreads();
  if ((tid & 63) == 0) red[tid >> 6] = su;
  __syncthreads();
  su = red[0] + red[1] + red[2] + red[3];   // waves 0-3 cover all 256 s
  float wgt = e / su;
  ws[s8] = wgt;                       // duplicate identical writes are benign
  if (qh == 0 && tid < 256) attn_out[((size_t)b * NT + t) * NS + tid] = wgt;
  __syncthreads();
  const int w8 = tid >> 6, l = tid & 63;
  const int h = (qh << 8) + (l << 2);
  const int s0 = w8 << 5;
  float4 a = make_float4(0.f, 0.f, 0.f, 0.f);
  if (use_8) {
    const unsigned char* ep = enc8 + ((size_t)b * NS + s0) * NH + h;
#pragma unroll 4
    for (int s = 0; s < 32; ++s) {
      int u = *(const int*)(ep + (size_t)s * NH);
      float wv = ws[s0 + s];
      a.x += wv * __builtin_amdgcn_cvt_f32_fp8(u, 0);
      a.y += wv * __builtin_amdgcn_cvt_f32_fp8(u, 1);
      a.z += wv * __builtin_amdgcn_cvt_f32_fp8(u, 2);
      a.w += wv * __builtin_amdgcn_cvt_f32_fp8(u, 3);
    }
  } else if (use_h) {
    const short* ep = enc_h + ((size_t)b * NS + s0) * NH + h;
    for (int s = 0; s < 32; ++s) {
      short4 vv = *(const short4*)(ep + (size_t)s * NH);
      float wv = ws[s0 + s];
      a.x += wv * B2F(vv.x); a.y += wv * B2F(vv.y);
      a.z += wv * B2F(vv.z); a.w += wv * B2F(vv.w);
    }
  } else {
    const float* ep = enc_f + ((size_t)b * NS + s0) * NH + h;
    for (int s = 0; s < 32; ++s) {
      float4 vv = *(const float4*)(ep + (size_t)s * NH);
      float wv = ws[s0 + s];
      a.x += wv * vv.x; a.y += wv * vv.y; a.z += wv * vv.z; a.w += wv * vv.w;
    }
  }
  red4[(w8 << 6) + l] = a;
  __syncthreads();
  if (tid < 64) {
    float sx = 0.f, sy = 0.f, sz = 0.f, sw = 0.f;
#pragma unroll
    for (int k = 0; k < 8; ++k) {
      float4 r = red4[(k << 6) + tid];
      sx += r.x; sy += r.y; sz += r.z; sw += r.w;
    }
    short4 o;
    o.x = F2B(sx); o.y = F2B(sy); o.z = F2B(sz); o.w = F2B(sw);
    *(short4*)(Xt + (size_t)b * NEH + NE + (qh << 8) + (tid << 2)) = o;
  }
}

// ---------------------------------------------------------------------------
extern "C" void kernel_launch(void* const* d_in, const int* in_sizes, int n_in,
                              void* d_out, int out_size, void* d_ws, size_t ws_size,
                              hipStream_t stream)
{
  const float* enc    = (const float*)d_in[0];
  const float* h0     = (const float*)d_in[1];
  const float* c0     = (const float*)d_in[2];
  const int*   target = (const int*)d_in[3];
  const unsigned char* mask = (const unsigned char*)d_in[4];
  const int*   sos    = (const int*)d_in[5];
  const float* emb    = (const float*)d_in[6];
  const float* Wa     = (const float*)d_in[7];
  const float* Ua     = (const float*)d_in[8];
  const float* Va     = (const float*)d_in[9];
  const float* out_W  = (const float*)d_in[10];
  const float* out_b  = (const float*)d_in[11];
  const float* Wih_f  = (const float*)d_in[12];
  const float* Whh_f  = (const float*)d_in[13];
  const float* bih_f  = (const float*)d_in[14];
  const float* bhh_f  = (const float*)d_in[15];
  const float* Wih_b  = (const float*)d_in[16];
  const float* Whh_b  = (const float*)d_in[17];
  const float* bih_b  = (const float*)d_in[18];
  const float* bhh_b  = (const float*)d_in[19];

  float* out_dec  = (float*)d_out;                       // [B][T][V]
  float* out_h    = out_dec + (size_t)NB * NT * NV;      // [2][B][D]
  float* out_c    = out_h + 2 * NB * ND;                 // [2][B][D]
  float* out_attn = out_c + 2 * NB * ND;                 // [B][T][S]

  char* base = (char*)d_ws;
  size_t off = 0;
  auto alloc = [&](size_t bytes) -> char* {
    char* p = base + off;
    off += (bytes + 255) & ~(size_t)255;
    return p;
  };
  short* Uk_h  = (short*)alloc((size_t)NB * NS * NH * 2);     // 33.5 MB
  short* ow_h  = (short*)alloc((size_t)NV * NH * 2);          // 20.5 MB
  short* Ua_h  = (short*)alloc((size_t)NH * NH * 2);
  short* Wa_h  = (short*)alloc((size_t)NH * NH * 2);
  short* Wcomb = (short*)alloc((size_t)2 * 2048 * 2048 * 2);  // 16.8 MB
  float* bperm = (float*)alloc((size_t)2 * 2048 * 4);
  float* q     = (float*)alloc((size_t)NB * NH * 4);
  float* sc    = (float*)alloc((size_t)NB * NS * 4);
  short* Xbuf  = (short*)alloc((size_t)NT * NB * NEH * 2);    // 12.6 MB
  float* hq    = (float*)alloc((size_t)NB * NH * 4);
  float* cq    = (float*)alloc((size_t)2 * NB * NH * 4);
  short* Hbuf  = (short*)alloc((size_t)NB * HST * 2);         // 8.5 MB [b][65][NH]
  short* enc_h = nullptr;
  unsigned char* enc8 = nullptr;
  int use_h = 0, use_8 = 0;
  if (off + (size_t)NB * NS * NH * 2 <= ws_size) {
    enc_h = (short*)alloc((size_t)NB * NS * NH * 2);          // 33.5 MB
    use_h = 1;
    if (off + (size_t)NB * NS * NH <= ws_size) {
      enc8 = (unsigned char*)alloc((size_t)NB * NS * NH);     // 16.8 MB
      use_8 = 1;
    }
  }
  if (off > ws_size) return;  // insufficient scratch

  // ---- setup ----
  f2b_k<<<dim3(2048), dim3(256), 0, stream>>>(out_W, ow_h, NV * NH / 4);
  f2b2_k<<<dim3(2048), dim3(256), 0, stream>>>(Ua, Ua_h, Wa, Wa_h, NH * NH / 4);
  perm_w<<<dim3(8192), dim3(256), 0, stream>>>(Wih_f, Whh_f, Wih_b, Whh_b,
                                               bih_f, bhh_f, bih_b, bhh_b,
                                               Wcomb, bperm);
  emb_fill<<<dim3(2048), dim3(256), 0, stream>>>(emb, target, sos, Xbuf);
  init_state<<<dim3(256), dim3(256), 0, stream>>>(h0, c0, hq, cq, Hbuf);
  if (use_h) {
    f2b8_k<<<dim3(2048), dim3(256), 0, stream>>>(enc, enc_h, (unsigned*)enc8,
                                                 NB * NS * NH / 4);
    mm128p<1><<<dim3(128, 8), dim3(256), 0, stream>>>(enc_h, Ua_h, NH, nullptr,
                                                      nullptr, Uk_h);
  } else {
    uk_mm_f32<<<dim3(16, 256), dim3(256), 0, stream>>>(enc, Ua_h, Uk_h);
  }

  // ---- recurrent loop: 4 kernels per step ----
  for (int t = 0; t < NT; ++t) {
    const short* hcur = Hbuf + (size_t)t * NH;        // row b at + b*HST
    short* hnext = Hbuf + (size_t)(t + 1) * NH;
    float* cq_cur = cq + (t & 1) * (NB * NH);
    float* cq_nxt = cq + ((t & 1) ^ 1) * (NB * NH);
    short* Xt = Xbuf + (size_t)t * NB * NEH;

    q_mm2<<<dim3(64), dim3(256), 0, stream>>>(hcur, Wa_h, q);
    attn_score<<<dim3(4096), dim3(256), 0, stream>>>(q, Uk_h, Va, mask, sc);
    ctx_soft<<<dim3(256), dim3(512), 0, stream>>>(sc, enc8, enc_h, enc,
                                                  use_8, use_h,
                                                  Xt, out_attn, t);
    gates_v2<<<dim3(256), dim3(256), 0, stream>>>(Xt, hcur, Wcomb, bperm,
                                                  cq_cur, hq, cq_nxt, hnext);
  }

  // ---- batched vocab projection over all steps (A rows mapped from Hbuf) --
  mm128p<0><<<dim3(32, 79), dim3(256), 0, stream>>>(Hbuf, ow_h, NV,
                                                    out_b, out_dec, nullptr);
  final_state<<<dim3(256), dim3(256), 0, stream>>>(hq, cq, out_h, out_c);
}

// Round 14
// 1841.927 us; speedup vs baseline: 1.2067x; 1.0706x over previous
//
#include <hip/hip_runtime.h>

#define NB 64
#define NS 256
#define NH 1024
#define NE 512
#define NV 10000
#define NT 64
#define ND 512
#define NEH 1536
#define HST (65 * NH)   // element stride between batches in Hbuf[b][t][:]

typedef __attribute__((ext_vector_type(8))) short bf16x8;
typedef __attribute__((ext_vector_type(4))) float f32x4;

__device__ __forceinline__ short F2B(float f) {
  unsigned u = __float_as_uint(f);
  return (short)((u + 0x7fffu + ((u >> 16) & 1u)) >> 16);
}
__device__ __forceinline__ float B2F(short s) {
  return __uint_as_float(((unsigned)(unsigned short)s) << 16);
}
__device__ __forceinline__ float ftanh(float x) {
  float e = __expf(2.f * x);                 // inf for big x -> rcp -> 0 -> 1
  return 1.f - 2.f * __builtin_amdgcn_rcpf(e + 1.f);
}

#define GLD16(src, dst)                                                        \
  __builtin_amdgcn_global_load_lds(                                            \
      (const __attribute__((address_space(1))) void*)(src),                    \
      (__attribute__((address_space(3))) void*)(dst), 16, 0, 0)

// ---------------------------------------------------------------------------
// Fallback 64x64 tile (fp32 A staging) — used only for Uk when enc_h absent.
// ---------------------------------------------------------------------------
__device__ __forceinline__ void mm64_f32a(
    const float* __restrict__ Af, int lda, const short* __restrict__ Wg,
    int ldw, int K, short* Ch, size_t ldc, char* smem)
{
  const int tid = threadIdx.x;
  const int lane = tid & 63, w = tid >> 6;
  const int qm = (w >> 1) << 5, qn = (w & 1) << 5;
  const int kg = lane >> 4, rl = lane & 15;
  f32x4 acc[2][2] = {};
  const int nIt = K >> 6;

  auto stage = [&](int k0, int buf) {
    char* As = smem + (buf << 14);
    char* Bs = As + 8192;
#pragma unroll
    for (int p = 0; p < 2; ++p) {
      int j = tid + (p << 8);
      int row = j >> 3;
      int c = (j & 7) ^ (row & 7);
      const float* src = Af + (size_t)row * lda + k0 + (c << 3);
      float4 v0 = ((const float4*)src)[0];
      float4 v1 = ((const float4*)src)[1];
      bf16x8 pk;
      pk[0] = F2B(v0.x); pk[1] = F2B(v0.y); pk[2] = F2B(v0.z); pk[3] = F2B(v0.w);
      pk[4] = F2B(v1.x); pk[5] = F2B(v1.y); pk[6] = F2B(v1.z); pk[7] = F2B(v1.w);
      *((bf16x8*)As + j) = pk;
    }
#pragma unroll
    for (int p = 0; p < 2; ++p) {
      int j = (w << 7) + (p << 6) + lane;
      int row = j >> 3;
      int c = (j & 7) ^ (row & 7);
      GLD16(Wg + (size_t)row * ldw + k0 + (c << 3), Bs + (w << 11) + (p << 10));
    }
  };

  stage(0, 0);
  for (int it = 0; it < nIt; ++it) {
    __syncthreads();
    if (it + 1 < nIt) stage((it + 1) << 6, (it + 1) & 1);
    const short* As = (const short*)(smem + ((it & 1) << 14));
    const short* Bs = As + 4096;
#pragma unroll
    for (int kk = 0; kk < 2; ++kk) {
      bf16x8 af[2], bfr[2];
#pragma unroll
      for (int mt = 0; mt < 2; ++mt) {
        int r2 = qm + (mt << 4) + rl;
        int c = (kk << 2) + kg;
        af[mt] = *((const bf16x8*)As + ((r2 << 3) | (c ^ (r2 & 7))));
      }
#pragma unroll
      for (int nt = 0; nt < 2; ++nt) {
        int r2 = qn + (nt << 4) + rl;
        int c = (kk << 2) + kg;
        bfr[nt] = *((const bf16x8*)Bs + ((r2 << 3) | (c ^ (r2 & 7))));
      }
#pragma unroll
      for (int mt = 0; mt < 2; ++mt)
#pragma unroll
        for (int nt = 0; nt < 2; ++nt)
          acc[mt][nt] = __builtin_amdgcn_mfma_f32_16x16x32_bf16(
              af[mt], bfr[nt], acc[mt][nt], 0, 0, 0);
    }
  }
#pragma unroll
  for (int mt = 0; mt < 2; ++mt)
#pragma unroll
    for (int nt = 0; nt < 2; ++nt) {
      int cn = qn + (nt << 4) + rl;
#pragma unroll
      for (int r = 0; r < 4; ++r) {
        int rowm = qm + (mt << 4) + (kg << 2) + r;
        Ch[(size_t)rowm * ldc + cn] = F2B(acc[mt][nt][r]);
      }
    }
}

__global__ __launch_bounds__(256) void uk_mm_f32(const float* __restrict__ enc,
                                                 const short* __restrict__ Ua_h,
                                                 short* __restrict__ Uk_h) {
  __shared__ char smem[32768];
  mm64_f32a(enc + (size_t)blockIdx.y * 64 * NH, NH,
            Ua_h + (size_t)blockIdx.x * 64 * NH, NH, NH,
            Uk_h + (size_t)blockIdx.y * 64 * NH + blockIdx.x * 64, NH, smem);
}

// ---------------------------------------------------------------------------
// 128x128 bf16 tile GEMM, 2-deep pipelined LDS. Grid: x = m-tile, y = n-tile.
// MODE 0 = logits: A rows from Hbuf[b][t] via arow(m)=(m>>6)*65+(m&63)+1,
//          contiguous [B][T][V] fp32 store + bias.
// MODE 1 = Uk (plain A rows, bf16 store).
// ---------------------------------------------------------------------------
template <int MODE>
__global__ __launch_bounds__(256) void mm128p(
    const short* __restrict__ A, const short* __restrict__ Bw, int nvmax,
    const float* __restrict__ bias, float* __restrict__ Cf,
    short* __restrict__ Ch)
{
  __shared__ char smem[65536];
  const int tid = threadIdx.x, lane = tid & 63, w = tid >> 6;
  const int m0 = blockIdx.x << 7;
  const int n0 = blockIdx.y << 7;
  const int qm = (w >> 1) << 6, qn = (w & 1) << 6;
  const int kg = lane >> 4, rl = lane & 15;
  f32x4 acc[4][4] = {};

  auto stage = [&](int it, int buf) {
    char* dst = smem + (buf << 15);
    const int k0 = it << 6;
#pragma unroll
    for (int p = 0; p < 4; ++p) {
      int j = (((w << 2) + p) << 6) + lane;
      int row = j >> 3;
      int c = (j & 7) ^ (row & 7);
      int m = m0 + row;
      size_t arow = (MODE == 0) ? ((size_t)(m >> 6) * 65 + (m & 63) + 1)
                                : (size_t)m;
      GLD16(A + arow * NH + k0 + (c << 3), dst + (((w << 2) + p) << 10));
      int vr = n0 + row; if (vr > nvmax - 1) vr = nvmax - 1;
      GLD16(Bw + (size_t)vr * NH + k0 + (c << 3),
            dst + 16384 + (((w << 2) + p) << 10));
    }
  };

  stage(0, 0); stage(1, 1);
  for (int it = 0; it < 16; ++it) {
    if (it < 15) asm volatile("s_waitcnt vmcnt(8)" ::: "memory");
    else         asm volatile("s_waitcnt vmcnt(0)" ::: "memory");
    __builtin_amdgcn_s_barrier();
    __builtin_amdgcn_sched_barrier(0);
    const short* As = (const short*)(smem + ((it & 1) << 15));
    const short* Bs = As + 8192;
#pragma unroll
    for (int kk = 0; kk < 2; ++kk) {
      bf16x8 af[4], bfr[4];
#pragma unroll
      for (int mt = 0; mt < 4; ++mt) {
        int r2 = qm + (mt << 4) + rl;
        int c = (kk << 2) + kg;
        af[mt] = *((const bf16x8*)As + ((r2 << 3) | (c ^ (r2 & 7))));
      }
#pragma unroll
      for (int nt = 0; nt < 4; ++nt) {
        int r2 = qn + (nt << 4) + rl;
        int c = (kk << 2) + kg;
        bfr[nt] = *((const bf16x8*)Bs + ((r2 << 3) | (c ^ (r2 & 7))));
      }
#pragma unroll
      for (int mt = 0; mt < 4; ++mt)
#pragma unroll
        for (int nt = 0; nt < 4; ++nt)
          acc[mt][nt] = __builtin_amdgcn_mfma_f32_16x16x32_bf16(
              af[mt], bfr[nt], acc[mt][nt], 0, 0, 0);
    }
    __builtin_amdgcn_sched_barrier(0);
    __builtin_amdgcn_s_barrier();
    if (it + 2 < 16) stage(it + 2, it & 1);
  }
#pragma unroll
  for (int nt = 0; nt < 4; ++nt) {
    int colv = n0 + qn + (nt << 4) + rl;
    if (colv < nvmax) {
#pragma unroll
      for (int mt = 0; mt < 4; ++mt)
#pragma unroll
        for (int r = 0; r < 4; ++r) {
          int m = m0 + qm + (mt << 4) + (kg << 2) + r;
          if (MODE == 0) {
            Cf[(size_t)m * NV + colv] = acc[mt][nt][r] + bias[colv];
          } else {
            Ch[(size_t)m * NH + colv] = F2B(acc[mt][nt][r]);
          }
        }
    }
  }
}

// ---------------------------------------------------------------------------
// Setup GEMM: Gemb[m=t*64+b][n=0..4095] = Xbuf[m][0:512] . Wcomb[n][0:512]
// 128x128 tile, K=512 (8 iters), 2-deep pipeline, bf16 store (ldc 4096).
// ---------------------------------------------------------------------------
__global__ __launch_bounds__(256) void emb_mm(
    const short* __restrict__ A, const short* __restrict__ Bw,
    short* __restrict__ Ch)
{
  __shared__ char smem[65536];
  const int tid = threadIdx.x, lane = tid & 63, w = tid >> 6;
  const int m0 = blockIdx.x << 7;
  const int n0 = blockIdx.y << 7;
  const int qm = (w >> 1) << 6, qn = (w & 1) << 6;
  const int kg = lane >> 4, rl = lane & 15;
  f32x4 acc[4][4] = {};

  auto stage = [&](int it, int buf) {
    char* dst = smem + (buf << 15);
    const int k0 = it << 6;
#pragma unroll
    for (int p = 0; p < 4; ++p) {
      int j = (((w << 2) + p) << 6) + lane;
      int row = j >> 3;
      int c = (j & 7) ^ (row & 7);
      GLD16(A + (size_t)(m0 + row) * NEH + k0 + (c << 3),
            dst + (((w << 2) + p) << 10));
      GLD16(Bw + (size_t)(n0 + row) * 2048 + k0 + (c << 3),
            dst + 16384 + (((w << 2) + p) << 10));
    }
  };

  stage(0, 0); stage(1, 1);
  for (int it = 0; it < 8; ++it) {
    if (it < 7) asm volatile("s_waitcnt vmcnt(8)" ::: "memory");
    else        asm volatile("s_waitcnt vmcnt(0)" ::: "memory");
    __builtin_amdgcn_s_barrier();
    __builtin_amdgcn_sched_barrier(0);
    const short* As = (const short*)(smem + ((it & 1) << 15));
    const short* Bs = As + 8192;
#pragma unroll
    for (int kk = 0; kk < 2; ++kk) {
      bf16x8 af[4], bfr[4];
#pragma unroll
      for (int mt = 0; mt < 4; ++mt) {
        int r2 = qm + (mt << 4) + rl;
        int c = (kk << 2) + kg;
        af[mt] = *((const bf16x8*)As + ((r2 << 3) | (c ^ (r2 & 7))));
      }
#pragma unroll
      for (int nt = 0; nt < 4; ++nt) {
        int r2 = qn + (nt << 4) + rl;
        int c = (kk << 2) + kg;
        bfr[nt] = *((const bf16x8*)Bs + ((r2 << 3) | (c ^ (r2 & 7))));
      }
#pragma unroll
      for (int mt = 0; mt < 4; ++mt)
#pragma unroll
        for (int nt = 0; nt < 4; ++nt)
          acc[mt][nt] = __builtin_amdgcn_mfma_f32_16x16x32_bf16(
              af[mt], bfr[nt], acc[mt][nt], 0, 0, 0);
    }
    __builtin_amdgcn_sched_barrier(0);
    __builtin_amdgcn_s_barrier();
    if (it + 2 < 8) stage(it + 2, it & 1);
  }
#pragma unroll
  for (int nt = 0; nt < 4; ++nt) {
    int colv = n0 + qn + (nt << 4) + rl;
#pragma unroll
    for (int mt = 0; mt < 4; ++mt)
#pragma unroll
      for (int r = 0; r < 4; ++r) {
        int m = m0 + qm + (mt << 4) + (kg << 2) + r;
        Ch[(size_t)m * 4096 + colv] = F2B(acc[mt][nt][r]);
      }
  }
}

// ---------------------------------------------------------------------------
// Pipelined skinny GEMM + fused LSTM cell. Grid 256 = dir(2) x gi(128).
// USEG=1: emb-gate contribution precomputed (Gemb_t), K = ctx(1024)+h(512);
// USEG=0: original K = x(1536)+h(512).
// ---------------------------------------------------------------------------
template <int USEG>
__global__ __launch_bounds__(256) void gates_v2(
    const short* __restrict__ Xt, const short* __restrict__ hcur,
    const short* __restrict__ Wcomb, const float* __restrict__ bperm,
    const float* __restrict__ cq_old, float* __restrict__ hq_f,
    float* __restrict__ cq_new, short* __restrict__ hnext,
    const short* __restrict__ Gemb_t)
{
  __shared__ char smem[61440];
  const int tid = threadIdx.x, lane = tid & 63, w = tid >> 6;
  const int kg = lane >> 4, rl = lane & 15;
  const int dir = blockIdx.x >> 7, gi = blockIdx.x & 127;
  const int hoff = dir << 9;
  const short* Wbase = Wcomb + (((size_t)(dir << 11) + (gi << 4)) << 11);
  const int NIT = USEG ? 12 : 16;
  const int KB0 = USEG ? 512 : 0;        // weight K base offset
  const int XOFF = USEG ? 512 : 0;       // activation x base offset
  const int HBND = USEG ? 1024 : NEH;    // activation boundary x->h

  auto stage = [&](int it, int buf) {
    char* dst = smem + buf * 20480;
#pragma unroll
    for (int g = 0; g < 4; ++g) {
      int row = (g << 4) + (w << 2) + kg;
      int c = rl ^ (row & 15);
      int k = (it << 7) + (c << 3);
      const short* src = (k < HBND)
          ? (Xt + (size_t)row * NEH + XOFF + k)
          : (hcur + (size_t)row * HST + hoff + (k - HBND));
      GLD16(src, dst + (g << 12) + (w << 10));
    }
    {
      int rowB = (w << 2) + kg;
      int cB = rl ^ rowB;
      int kB = (it << 7) + (cB << 3);
      GLD16(Wbase + (size_t)rowB * 2048 + KB0 + kB, dst + 16384 + (w << 10));
    }
  };

  stage(0, 0); stage(1, 1); stage(2, 2);
  f32x4 acc = {};
  int buf = 0;
  for (int it = 0; it < NIT; ++it) {
    if (it < NIT - 2)       asm volatile("s_waitcnt vmcnt(10)" ::: "memory");
    else if (it == NIT - 2) asm volatile("s_waitcnt vmcnt(5)" ::: "memory");
    else                    asm volatile("s_waitcnt vmcnt(0)" ::: "memory");
    __builtin_amdgcn_s_barrier();
    __builtin_amdgcn_sched_barrier(0);
    const short* As = (const short*)(smem + buf * 20480);
    const short* Bs = (const short*)(smem + buf * 20480 + 16384);
    const int rowA = (w << 4) + rl;
#pragma unroll
    for (int kk = 0; kk < 4; ++kk) {
      int chunk = (kk << 2) | kg;
      bf16x8 af = *((const bf16x8*)As + ((rowA << 4) | (chunk ^ (rowA & 15))));
      bf16x8 bf = *((const bf16x8*)Bs + ((rl << 4) | (chunk ^ rl)));
      acc = __builtin_amdgcn_mfma_f32_16x16x32_bf16(af, bf, acc, 0, 0, 0);
    }
    __builtin_amdgcn_sched_barrier(0);
    __builtin_amdgcn_s_barrier();
    if (it + 3 < NIT) stage(it + 3, buf);
    buf = (buf == 2) ? 0 : buf + 1;
  }
  float* gacc = (float*)smem;                    // [64][17], overlays buf0
#pragma unroll
  for (int r = 0; r < 4; ++r)
    gacc[((w << 4) + (kg << 2) + r) * 17 + rl] = acc[r];
  __syncthreads();
  {
    const int b = tid >> 2, j2 = tid & 3;
    const float* bp = bperm + (dir << 11) + (gi << 4) + (j2 << 2);
    const float* gr = gacc + b * 17 + (j2 << 2);
    float gi_ = gr[0] + bp[0];
    float gf_ = gr[1] + bp[1];
    float gg_ = gr[2] + bp[2];
    float go_ = gr[3] + bp[3];
    if (USEG) {
      short4 ge = *(const short4*)(Gemb_t + (size_t)b * 4096 + (dir << 11) +
                                   (gi << 4) + (j2 << 2));
      gi_ += B2F(ge.x); gf_ += B2F(ge.y); gg_ += B2F(ge.z); go_ += B2F(ge.w);
    }
    const int d = ((gi >> 2) << 4) + (((gi << 2) + j2) & 15);
    const int idx = (b << 10) + hoff + d;
    float c0v = cq_old[idx];
    float si = 1.f / (1.f + __expf(-gi_));
    float sf = 1.f / (1.f + __expf(-gf_));
    float so = 1.f / (1.f + __expf(-go_));
    float tg = ftanh(gg_);
    float c2 = sf * c0v + si * tg;
    float h2 = so * ftanh(c2);
    hq_f[idx] = h2;
    cq_new[idx] = c2;
    hnext[(size_t)b * HST + hoff + d] = F2B(h2);
  }
}

// ---------------------------------------------------------------------------
// Pipelined q GEMM: grid 64 blocks, M=64, N=16, K=1024, BK=128, 3-deep.
// h rows read at HST stride.
// ---------------------------------------------------------------------------
__global__ __launch_bounds__(256) void q_mm2(const short* __restrict__ hcur,
                                             const short* __restrict__ Wa_h,
                                             float* __restrict__ q)
{
  __shared__ char smem[61440];
  const int tid = threadIdx.x, lane = tid & 63, w = tid >> 6;
  const int kg = lane >> 4, rl = lane & 15;
  const int n0 = blockIdx.x << 4;
  const short* Wbase = Wa_h + (size_t)n0 * NH;

  auto stage = [&](int it, int buf) {
    char* dst = smem + buf * 20480;
#pragma unroll
    for (int g = 0; g < 4; ++g) {
      int row = (g << 4) + (w << 2) + kg;
      int c = rl ^ (row & 15);
      int k = (it << 7) + (c << 3);
      GLD16(hcur + (size_t)row * HST + k, dst + (g << 12) + (w << 10));
    }
    {
      int rowB = (w << 2) + kg;
      int cB = rl ^ rowB;
      int kB = (it << 7) + (cB << 3);
      GLD16(Wbase + (size_t)rowB * NH + kB, dst + 16384 + (w << 10));
    }
  };

  stage(0, 0); stage(1, 1); stage(2, 2);
  f32x4 acc = {};
  int buf = 0;
  for (int it = 0; it < 8; ++it) {
    if (it < 6)       asm volatile("s_waitcnt vmcnt(10)" ::: "memory");
    else if (it == 6) asm volatile("s_waitcnt vmcnt(5)" ::: "memory");
    else              asm volatile("s_waitcnt vmcnt(0)" ::: "memory");
    __builtin_amdgcn_s_barrier();
    __builtin_amdgcn_sched_barrier(0);
    const short* As = (const short*)(smem + buf * 20480);
    const short* Bs = (const short*)(smem + buf * 20480 + 16384);
    const int rowA = (w << 4) + rl;
#pragma unroll
    for (int kk = 0; kk < 4; ++kk) {
      int chunk = (kk << 2) | kg;
      bf16x8 af = *((const bf16x8*)As + ((rowA << 4) | (chunk ^ (rowA & 15))));
      bf16x8 bf = *((const bf16x8*)Bs + ((rl << 4) | (chunk ^ rl)));
      acc = __builtin_amdgcn_mfma_f32_16x16x32_bf16(af, bf, acc, 0, 0, 0);
    }
    __builtin_amdgcn_sched_barrier(0);
    __builtin_amdgcn_s_barrier();
    if (it + 3 < 8) stage(it + 3, buf);
    buf = (buf == 2) ? 0 : buf + 1;
  }
#pragma unroll
  for (int r = 0; r < 4; ++r)
    q[(size_t)((w << 4) + (kg << 2) + r) * NH + n0 + rl] = acc[r];
}

// --- small kernels ----------------------------------------------------------
__global__ __launch_bounds__(256) void f2b_k(const float* __restrict__ in,
                                             short* __restrict__ out, int n4) {
  int i = blockIdx.x * 256 + threadIdx.x;
  const int stride = gridDim.x * 256;
  for (; i < n4; i += stride) {
    float4 v = ((const float4*)in)[i];
    short4 o;
    o.x = F2B(v.x); o.y = F2B(v.y); o.z = F2B(v.z); o.w = F2B(v.w);
    ((short4*)out)[i] = o;
  }
}

// fp32 -> bf16 AND fp8(e4m3) in one pass (for enc)
__global__ __launch_bounds__(256) void f2b8_k(const float* __restrict__ in,
                                              short* __restrict__ outb,
                                              unsigned* __restrict__ out8,
                                              int n4) {
  int i = blockIdx.x * 256 + threadIdx.x;
  const int stride = gridDim.x * 256;
  for (; i < n4; i += stride) {
    float4 v = ((const float4*)in)[i];
    short4 o;
    o.x = F2B(v.x); o.y = F2B(v.y); o.z = F2B(v.z); o.w = F2B(v.w);
    ((short4*)outb)[i] = o;
    if (out8) {
      int u = __builtin_amdgcn_cvt_pk_fp8_f32(v.x, v.y, 0, false);
      u = __builtin_amdgcn_cvt_pk_fp8_f32(v.z, v.w, u, true);
      out8[i] = (unsigned)u;
    }
  }
}

__global__ __launch_bounds__(256) void f2b2_k(
    const float* __restrict__ in0, short* __restrict__ out0,
    const float* __restrict__ in1, short* __restrict__ out1, int n4each) {
  int i = blockIdx.x * 256 + threadIdx.x;
  const int stride = gridDim.x * 256;
  for (; i < 2 * n4each; i += stride) {
    const float* in = (i < n4each) ? in0 : in1;
    short* out = (i < n4each) ? out0 : out1;
    int j = (i < n4each) ? i : i - n4each;
    float4 v = ((const float4*)in)[j];
    short4 o;
    o.x = F2B(v.x); o.y = F2B(v.y); o.z = F2B(v.z); o.w = F2B(v.w);
    ((short4*)out)[j] = o;
  }
}

__global__ __launch_bounds__(256) void perm_w(
    const float* __restrict__ Wih_f, const float* __restrict__ Whh_f,
    const float* __restrict__ Wih_b, const float* __restrict__ Whh_b,
    const float* __restrict__ bih_f, const float* __restrict__ bhh_f,
    const float* __restrict__ bih_b, const float* __restrict__ bhh_b,
    short* __restrict__ Wcomb, float* __restrict__ bias_perm)
{
  int i = blockIdx.x * 256 + threadIdx.x;        // [0, 2*2048*512)
  int k4 = i & 511;
  int np = (i >> 9) & 2047;
  int dir = i >> 20;
  int gate = np & 3, dlo = (np >> 2) & 15, dblk = np >> 6;
  int d = (dblk << 4) + dlo;
  int r = (gate << 9) + d;
  int k = k4 << 2;
  const float* Wih = dir ? Wih_b : Wih_f;
  const float* Whh = dir ? Whh_b : Whh_f;
  float4 v = (k < NEH) ? *(const float4*)(Wih + (size_t)r * NEH + k)
                       : *(const float4*)(Whh + (size_t)r * ND + (k - NEH));
  short4 o;
  o.x = F2B(v.x); o.y = F2B(v.y); o.z = F2B(v.z); o.w = F2B(v.w);
  *(short4*)(Wcomb + ((size_t)((dir << 11) + np) << 11) + k) = o;
  if (k4 == 0) {
    const float* bi = dir ? bih_b : bih_f;
    const float* bh = dir ? bhh_b : bhh_f;
    bias_perm[(dir << 11) + np] = bi[r] + bh[r];
  }
}

__global__ __launch_bounds__(256) void emb_fill(
    const float* __restrict__ emb, const int* __restrict__ target,
    const int* __restrict__ sos, short* __restrict__ Xbuf)
{
  int idx = blockIdx.x * 256 + threadIdx.x;      // [0, 64*64*128)
  int t = idx >> 13;
  int r = idx & 8191;
  int b = r >> 7, e4 = r & 127;
  int tok = (t == 0) ? sos[0] : target[b * NT + t - 1];
  float4 v = *(const float4*)(emb + (size_t)tok * NE + (e4 << 2));
  short4 o;
  o.x = F2B(v.x); o.y = F2B(v.y); o.z = F2B(v.z); o.w = F2B(v.w);
  *(short4*)(Xbuf + (size_t)(t * NB + b) * NEH + (e4 << 2)) = o;
}

__global__ __launch_bounds__(256) void init_state(
    const float* __restrict__ h0, const float* __restrict__ c0,
    float* __restrict__ hq, float* __restrict__ cq, short* __restrict__ H0) {
  int idx = blockIdx.x * 256 + threadIdx.x;
  int b = idx >> 10, dir = (idx >> 9) & 1, d = idx & 511;
  int src = dir * NB * ND + (b << 9) + d;
  float h = h0[src];
  hq[idx] = h;
  cq[idx] = c0[src];
  H0[(size_t)b * HST + (dir << 9) + d] = F2B(h);   // Hbuf[b][0][:]
}

__global__ __launch_bounds__(256) void final_state(
    const float* __restrict__ hq, const float* __restrict__ cq,
    float* __restrict__ out_h, float* __restrict__ out_c) {
  int idx = blockIdx.x * 256 + threadIdx.x;
  int dir = idx >> 15, r = idx & 32767, b = r >> 9, d = r & 511;
  int src = b * NH + dir * ND + d;
  out_h[idx] = hq[src];
  out_c[idx] = cq[src];
}

// one wave per (b,s); q[b] staged in LDS once per block (4 s per block)
// grid MUST be NB*NS/4 = 4096 blocks (b = blockIdx.x>>6).
__global__ __launch_bounds__(256) void attn_score(
    const float* __restrict__ q, const short* __restrict__ Uk,
    const float* __restrict__ Va, const unsigned char* __restrict__ mask,
    float* __restrict__ sc) {
  __shared__ float qs[NH];
  const int b = blockIdx.x >> 6;
  {
    int t4 = threadIdx.x << 2;
    *(float4*)(qs + t4) = *(const float4*)(q + (size_t)b * NH + t4);
  }
  __syncthreads();
  const int lane = threadIdx.x & 63, wid = threadIdx.x >> 6;
  const int bs = (blockIdx.x << 2) + wid;
  const short* ukp = Uk + (size_t)bs * NH;
  float acc = 0.f;
#pragma unroll
  for (int i = 0; i < 2; ++i) {
    int h = (i << 9) + (lane << 3);
    bf16x8 uv = *(const bf16x8*)(ukp + h);
    float4 q0 = *(const float4*)(qs + h);
    float4 q1 = *(const float4*)(qs + h + 4);
    float4 v0 = *(const float4*)(Va + h);
    float4 v1 = *(const float4*)(Va + h + 4);
    acc += v0.x * ftanh(q0.x + B2F(uv[0]));
    acc += v0.y * ftanh(q0.y + B2F(uv[1]));
    acc += v0.z * ftanh(q0.z + B2F(uv[2]));
    acc += v0.w * ftanh(q0.w + B2F(uv[3]));
    acc += v1.x * ftanh(q1.x + B2F(uv[4]));
    acc += v1.y * ftanh(q1.y + B2F(uv[5]));
    acc += v1.z * ftanh(q1.z + B2F(uv[6]));
    acc += v1.w * ftanh(q1.w + B2F(uv[7]));
  }
#pragma unroll
  for (int o = 32; o; o >>= 1) acc += __shfl_down(acc, o);
  if (lane == 0) sc[bs] = mask[bs] ? -__builtin_inff() : acc;
}

// 256 blocks x 512 threads: (b, h-quarter) softmax + ctx -> Xt[:, E:E+H]
// use_8: read fp8 e4m3 enc copy (half the stream) via HW cvt_f32_fp8.
__global__ __launch_bounds__(512) void ctx_soft(
    const float* __restrict__ sc, const unsigned char* __restrict__ enc8,
    const short* __restrict__ enc_h, const float* __restrict__ enc_f,
    int use_8, int use_h,
    short* __restrict__ Xt, float* __restrict__ attn_out, int t) {
  const int tid = threadIdx.x;
  const int b = blockIdx.x >> 2, qh = blockIdx.x & 3;
  __shared__ float red[8];
  __shared__ float ws[NS];
  __shared__ float4 red4[512];
  const int s8 = tid & 255;
  float v = sc[b * NS + s8];
  float m = v;
#pragma unroll
  for (int o = 32; o; o >>= 1) m = fmaxf(m, __shfl_down(m, o));
  if ((tid & 63) == 0) red[tid >> 6] = m;
  __syncthreads();
  m = fmaxf(fmaxf(fmaxf(red[0], red[1]), fmaxf(red[2], red[3])),
            fmaxf(fmaxf(red[4], red[5]), fmaxf(red[6], red[7])));
  float e = __expf(v - m);
  float su = e;
#pragma unroll
  for (int o = 32; o; o >>= 1) su += __shfl_down(su, o);
  __syncthreads();
  if ((tid & 63) == 0) red[tid >> 6] = su;
  __syncthreads();
  su = red[0] + red[1] + red[2] + red[3];   // waves 0-3 cover all 256 s
  float wgt = e / su;
  ws[s8] = wgt;                       // duplicate identical writes are benign
  if (qh == 0 && tid < 256) attn_out[((size_t)b * NT + t) * NS + tid] = wgt;
  __syncthreads();
  const int w8 = tid >> 6, l = tid & 63;
  const int h = (qh << 8) + (l << 2);
  const int s0 = w8 << 5;
  float4 a = make_float4(0.f, 0.f, 0.f, 0.f);
  if (use_8) {
    const unsigned char* ep = enc8 + ((size_t)b * NS + s0) * NH + h;
#pragma unroll 4
    for (int s = 0; s < 32; ++s) {
      int u = *(const int*)(ep + (size_t)s * NH);
      float wv = ws[s0 + s];
      a.x += wv * __builtin_amdgcn_cvt_f32_fp8(u, 0);
      a.y += wv * __builtin_amdgcn_cvt_f32_fp8(u, 1);
      a.z += wv * __builtin_amdgcn_cvt_f32_fp8(u, 2);
      a.w += wv * __builtin_amdgcn_cvt_f32_fp8(u, 3);
    }
  } else if (use_h) {
    const short* ep = enc_h + ((size_t)b * NS + s0) * NH + h;
    for (int s = 0; s < 32; ++s) {
      short4 vv = *(const short4*)(ep + (size_t)s * NH);
      float wv = ws[s0 + s];
      a.x += wv * B2F(vv.x); a.y += wv * B2F(vv.y);
      a.z += wv * B2F(vv.z); a.w += wv * B2F(vv.w);
    }
  } else {
    const float* ep = enc_f + ((size_t)b * NS + s0) * NH + h;
    for (int s = 0; s < 32; ++s) {
      float4 vv = *(const float4*)(ep + (size_t)s * NH);
      float wv = ws[s0 + s];
      a.x += wv * vv.x; a.y += wv * vv.y; a.z += wv * vv.z; a.w += wv * vv.w;
    }
  }
  red4[(w8 << 6) + l] = a;
  __syncthreads();
  if (tid < 64) {
    float sx = 0.f, sy = 0.f, sz = 0.f, sw = 0.f;
#pragma unroll
    for (int k = 0; k < 8; ++k) {
      float4 r = red4[(k << 6) + tid];
      sx += r.x; sy += r.y; sz += r.z; sw += r.w;
    }
    short4 o;
    o.x = F2B(sx); o.y = F2B(sy); o.z = F2B(sz); o.w = F2B(sw);
    *(short4*)(Xt + (size_t)b * NEH + NE + (qh << 8) + (tid << 2)) = o;
  }
}

// ---------------------------------------------------------------------------
extern "C" void kernel_launch(void* const* d_in, const int* in_sizes, int n_in,
                              void* d_out, int out_size, void* d_ws, size_t ws_size,
                              hipStream_t stream)
{
  const float* enc    = (const float*)d_in[0];
  const float* h0     = (const float*)d_in[1];
  const float* c0     = (const float*)d_in[2];
  const int*   target = (const int*)d_in[3];
  const unsigned char* mask = (const unsigned char*)d_in[4];
  const int*   sos    = (const int*)d_in[5];
  const float* emb    = (const float*)d_in[6];
  const float* Wa     = (const float*)d_in[7];
  const float* Ua     = (const float*)d_in[8];
  const float* Va     = (const float*)d_in[9];
  const float* out_W  = (const float*)d_in[10];
  const float* out_b  = (const float*)d_in[11];
  const float* Wih_f  = (const float*)d_in[12];
  const float* Whh_f  = (const float*)d_in[13];
  const float* bih_f  = (const float*)d_in[14];
  const float* bhh_f  = (const float*)d_in[15];
  const float* Wih_b  = (const float*)d_in[16];
  const float* Whh_b  = (const float*)d_in[17];
  const float* bih_b  = (const float*)d_in[18];
  const float* bhh_b  = (const float*)d_in[19];

  float* out_dec  = (float*)d_out;                       // [B][T][V]
  float* out_h    = out_dec + (size_t)NB * NT * NV;      // [2][B][D]
  float* out_c    = out_h + 2 * NB * ND;                 // [2][B][D]
  float* out_attn = out_c + 2 * NB * ND;                 // [B][T][S]

  char* base = (char*)d_ws;
  size_t off = 0;
  auto alloc = [&](size_t bytes) -> char* {
    char* p = base + off;
    off += (bytes + 255) & ~(size_t)255;
    return p;
  };
  short* Uk_h  = (short*)alloc((size_t)NB * NS * NH * 2);     // 33.5 MB
  short* ow_h  = (short*)alloc((size_t)NV * NH * 2);          // 20.5 MB
  short* Ua_h  = (short*)alloc((size_t)NH * NH * 2);
  short* Wa_h  = (short*)alloc((size_t)NH * NH * 2);
  short* Wcomb = (short*)alloc((size_t)2 * 2048 * 2048 * 2);  // 16.8 MB
  float* bperm = (float*)alloc((size_t)2 * 2048 * 4);
  float* q     = (float*)alloc((size_t)NB * NH * 4);
  float* sc    = (float*)alloc((size_t)NB * NS * 4);
  short* Xbuf  = (short*)alloc((size_t)NT * NB * NEH * 2);    // 12.6 MB
  float* hq    = (float*)alloc((size_t)NB * NH * 4);
  float* cq    = (float*)alloc((size_t)2 * NB * NH * 4);
  short* Hbuf  = (short*)alloc((size_t)NB * HST * 2);         // 8.5 MB [b][65][NH]
  short* enc_h = nullptr;
  unsigned char* enc8 = nullptr;
  short* Gemb = nullptr;
  int use_h = 0, use_8 = 0, use_g = 0;
  if (off + (size_t)NB * NS * NH * 2 <= ws_size) {
    enc_h = (short*)alloc((size_t)NB * NS * NH * 2);          // 33.5 MB
    use_h = 1;
    if (off + (size_t)NB * NS * NH <= ws_size) {
      enc8 = (unsigned char*)alloc((size_t)NB * NS * NH);     // 16.8 MB
      use_8 = 1;
      if (off + (size_t)NT * NB * 4096 * 2 <= ws_size) {
        Gemb = (short*)alloc((size_t)NT * NB * 4096 * 2);     // 33.5 MB
        use_g = 1;
      }
    }
  }
  if (off > ws_size) return;  // insufficient scratch

  // ---- setup ----
  f2b_k<<<dim3(2048), dim3(256), 0, stream>>>(out_W, ow_h, NV * NH / 4);
  f2b2_k<<<dim3(2048), dim3(256), 0, stream>>>(Ua, Ua_h, Wa, Wa_h, NH * NH / 4);
  perm_w<<<dim3(8192), dim3(256), 0, stream>>>(Wih_f, Whh_f, Wih_b, Whh_b,
                                               bih_f, bhh_f, bih_b, bhh_b,
                                               Wcomb, bperm);
  emb_fill<<<dim3(2048), dim3(256), 0, stream>>>(emb, target, sos, Xbuf);
  init_state<<<dim3(256), dim3(256), 0, stream>>>(h0, c0, hq, cq, Hbuf);
  if (use_h) {
    f2b8_k<<<dim3(2048), dim3(256), 0, stream>>>(enc, enc_h, (unsigned*)enc8,
                                                 NB * NS * NH / 4);
    mm128p<1><<<dim3(128, 8), dim3(256), 0, stream>>>(enc_h, Ua_h, NH, nullptr,
                                                      nullptr, Uk_h);
  } else {
    uk_mm_f32<<<dim3(16, 256), dim3(256), 0, stream>>>(enc, Ua_h, Uk_h);
  }
  if (use_g)
    emb_mm<<<dim3(32, 32), dim3(256), 0, stream>>>(Xbuf, Wcomb, Gemb);

  // ---- recurrent loop: 4 kernels per step ----
  for (int t = 0; t < NT; ++t) {
    const short* hcur = Hbuf + (size_t)t * NH;        // row b at + b*HST
    short* hnext = Hbuf + (size_t)(t + 1) * NH;
    float* cq_cur = cq + (t & 1) * (NB * NH);
    float* cq_nxt = cq + ((t & 1) ^ 1) * (NB * NH);
    short* Xt = Xbuf + (size_t)t * NB * NEH;

    q_mm2<<<dim3(64), dim3(256), 0, stream>>>(hcur, Wa_h, q);
    attn_score<<<dim3(4096), dim3(256), 0, stream>>>(q, Uk_h, Va, mask, sc);
    ctx_soft<<<dim3(256), dim3(512), 0, stream>>>(sc, enc8, enc_h, enc,
                                                  use_8, use_h,
                                                  Xt, out_attn, t);
    if (use_g)
      gates_v2<1><<<dim3(256), dim3(256), 0, stream>>>(
          Xt, hcur, Wcomb, bperm, cq_cur, hq, cq_nxt, hnext,
          Gemb + (size_t)t * NB * 4096);
    else
      gates_v2<0><<<dim3(256), dim3(256), 0, stream>>>(
          Xt, hcur, Wcomb, bperm, cq_cur, hq, cq_nxt, hnext, nullptr);
  }

  // ---- batched vocab projection over all steps (A rows mapped from Hbuf) --
  mm128p<0><<<dim3(32, 79), dim3(256), 0, stream>>>(Hbuf, ow_h, NV,
                                                    out_b, out_dec, nullptr);
  final_state<<<dim3(256), dim3(256), 0, stream>>>(hq, cq, out_h, out_c);
}